// Round 7
// baseline (354.767 us; speedup 1.0000x reference)
//
#include <hip/hip_runtime.h>
#include <math.h>

#define HIDDEN 128
#define NFILT 64
#define SCAN_B 1024
#define LUTK 2048   // LUT entries over w in [0,8]; lerp err ~5e-7
#define NXCD 8

typedef __attribute__((ext_vector_type(8))) short bf16x8;
typedef __attribute__((ext_vector_type(4))) float f32x4;
typedef __attribute__((ext_vector_type(4))) float f32x4v;
typedef __attribute__((ext_vector_type(2))) int i32x2;

__device__ __forceinline__ short f2bf(float f) {
    unsigned u = __float_as_uint(f);
    unsigned r = (u + 0x7fffu + ((u >> 16) & 1u)) >> 16;   // RNE
    return (short)r;
}
__device__ __forceinline__ float bf2f(unsigned short u) {
    return __uint_as_float(((unsigned)u) << 16);
}

// physical XCD id (0..7). Wave-uniform; verified working on gfx950 (m09).
__device__ __forceinline__ int xcc_id() {
    int x;
    asm volatile("s_getreg_b32 %0, hwreg(HW_REG_XCC_ID)" : "=s"(x));
    return x & (NXCD - 1);
}

// softplus via raw v_exp_f32/v_log_f32 (log2 domain): ~5 VALU instrs vs ~25+ for log1pf.
__device__ __forceinline__ float softplus_fast(float v) {
    float e = __builtin_amdgcn_exp2f(v * 1.4426950408889634f);
    float r = 0.69314718055994531f * __builtin_amdgcn_logf(1.0f + e);
    return (v > 80.f) ? v : r;   // exp2 overflow guard
}

// ---------------------------------------------------------------------------
// wsum[j] = sum_f Wf2[j][f]; bsum = sum_f bf2[f]   (fallback path only)
// ---------------------------------------------------------------------------
__global__ void wsum_kernel(const float* __restrict__ Wf2, const float* __restrict__ bf2,
                            float* __restrict__ wsum, float* __restrict__ bsum) {
    int j = threadIdx.x;  // 0..63
    float s = 0.f;
    for (int f = 0; f < NFILT; ++f) s += Wf2[j * NFILT + f];
    wsum[j] = s;
    if (j == 0) {
        float b = 0.f;
        for (int f = 0; f < NFILT; ++f) b += bf2[f];
        *bsum = b;
    }
}

__device__ __forceinline__ float edge_coeff(float w,
                                            const float* sW, const float* sB,
                                            const float* sS, float bsum) {
    float s = fmaf(w, 0.25f, -1.0f);          // w * (2/8) - 1
    float acc = bsum;
    #pragma unroll 8
    for (int j = 0; j < NFILT; ++j)
        acc += tanhf(fmaf(s, sW[j], sB[j])) * sS[j];
    float cut = (w <= 8.0f) ? 0.5f * (cosf(w * 0.39269908169872414f) + 1.0f) : 0.0f;
    return acc * cut;
}

// LUT over the scalar filter function g(w), w in [0,8], LUTK+1 samples
__global__ void lut_kernel(const float* __restrict__ Wf1, const float* __restrict__ bf1,
                           const float* __restrict__ wsum, const float* __restrict__ bsum,
                           float* __restrict__ lut) {
    int i = blockIdx.x * 256 + threadIdx.x;
    if (i > LUTK) return;
    float w = 8.0f * (float)i / (float)LUTK;
    lut[i] = edge_coeff(w, Wf1, bf1, wsum, *bsum);
}

__device__ __forceinline__ float lut_eval(const float* sl, float w) {
    float t = w * ((float)LUTK / 8.0f);
    t = fminf(fmaxf(t, 0.f), (float)LUTK);
    int i = (int)t;
    i = min(i, LUTK - 1);
    return fmaf(t - (float)i, sl[i + 1] - sl[i], sl[i]);
}

// ---------------------------------------------------------------------------
// Prep (fused): W1T/W2T bf16 transpose of Wi1/Wi2 (all blocks);
// block 0: wsum/bsum; block 1: BN fold.
// ---------------------------------------------------------------------------
__global__ void prep_w_kernel(const float* __restrict__ Wi1, const float* __restrict__ Wi2,
                              short* __restrict__ W1T, short* __restrict__ W2T,
                              const float* __restrict__ Wf2, const float* __restrict__ bf2,
                              float* __restrict__ wsum, float* __restrict__ bsum,
                              const float* __restrict__ bi2,
                              const float* __restrict__ gamma, const float* __restrict__ beta,
                              const float* __restrict__ mean, const float* __restrict__ var,
                              float* __restrict__ scf, float* __restrict__ shf) {
    int idx = blockIdx.x * 256 + threadIdx.x;   // 0..32767
    const float* src = (idx < 16384) ? Wi1 : Wi2;
    short* dst = (idx < 16384) ? W1T : W2T;
    int i = idx & 16383;
    int k = i >> 7, n = i & 127;
    dst[n * HIDDEN + k] = f2bf(src[i]);

    if (blockIdx.x == 0 && threadIdx.x < 64) {
        int j = threadIdx.x;
        float s = 0.f;
        for (int f = 0; f < NFILT; ++f) s += Wf2[j * NFILT + f];
        wsum[j] = s;
        if (j == 0) {
            float b = 0.f;
            for (int f = 0; f < NFILT; ++f) b += bf2[f];
            *bsum = b;
        }
    }
    if (blockIdx.x == 1 && threadIdx.x < HIDDEN) {
        int j = threadIdx.x;
        float sc = gamma[j] * rsqrtf(var[j] + 1e-3f);
        scf[j] = sc;
        shf[j] = (bi2[j] - mean[j]) * sc + beta[j];
    }
}

// ---------------------------------------------------------------------------
// Fused: x fp32 -> xq int8 per-row-scaled (streaming, NT reads) + XCD-local
// CSR count/rank. deg_x[xcd][N]: copy k is ONLY touched from physical XCD k,
// so a workgroup-scope atomic (global_atomic_add sc0, no sc1) legally executes
// in XCD k's own L2 — no device-coherence-point round trip, 8 L2s in parallel.
// rank packs (xcd<<24)|localrank; end-of-kernel L2 writeback publishes deg_x.
// ---------------------------------------------------------------------------
__global__ __launch_bounds__(256) void x2q_count_kernel(
    const float* __restrict__ x, signed char* __restrict__ xq,
    float* __restrict__ xscale, int N16,
    const int* __restrict__ rows, int* __restrict__ deg_x,
    int* __restrict__ rank, int E, int N) {
    int i = blockIdx.x * 256 + threadIdx.x;
    if (i < E) {
        int r = rows[i];
        int xcd = xcc_id();
        int lr = __hip_atomic_fetch_add(&deg_x[(size_t)xcd * N + r], 1,
                                        __ATOMIC_RELAXED, __HIP_MEMORY_SCOPE_WORKGROUP);
        rank[i] = (xcd << 24) | lr;
    }
    if (i < N16) {
        int node = i >> 4, lane = i & 15;
        const float* xp = &x[(size_t)node * HIDDEN + lane * 8];
        const f32x4v v0 = __builtin_nontemporal_load((const f32x4v*)xp);
        const f32x4v v1 = __builtin_nontemporal_load((const f32x4v*)(xp + 4));
        float v[8] = {v0[0], v0[1], v0[2], v0[3], v1[0], v1[1], v1[2], v1[3]};
        float m = 0.f;
        #pragma unroll
        for (int j = 0; j < 8; ++j) m = fmaxf(m, fabsf(v[j]));
        // reduce max across the 16 lanes of this node
        #pragma unroll
        for (int off = 8; off > 0; off >>= 1)
            m = fmaxf(m, __shfl_xor(m, off, 16));
        float si = (m > 0.f) ? 127.f / m : 0.f;
        int q[8];
        #pragma unroll
        for (int j = 0; j < 8; ++j) q[j] = __float2int_rn(v[j] * si);
        int lo = (q[0] & 0xff) | ((q[1] & 0xff) << 8) |
                 ((q[2] & 0xff) << 16) | ((q[3] & 0xff) << 24);
        int hi = (q[4] & 0xff) | ((q[5] & 0xff) << 8) |
                 ((q[6] & 0xff) << 16) | ((q[7] & 0xff) << 24);
        *(int2*)&xq[(size_t)node * HIDDEN + lane * 8] = make_int2(lo, hi);
        if (lane == 0) xscale[node] = m * (1.f / 127.f);
    }
}

// per-row exclusive scan over the 8 XCD copies; bases written back in place,
// total -> deg. 8 coalesced read+write sweeps of 400 KB each.
__global__ __launch_bounds__(256) void rowscan8_kernel(int* __restrict__ deg_x,
                                                       int* __restrict__ deg, int N) {
    int r = blockIdx.x * 256 + threadIdx.x;
    if (r >= N) return;
    int s = 0;
    #pragma unroll
    for (int c = 0; c < NXCD; ++c) {
        int v = deg_x[(size_t)c * N + r];
        deg_x[(size_t)c * N + r] = s;
        s += v;
    }
    deg[r] = s;
}

// non-fused variants (tier B path)
__global__ void count_rank_kernel(const int* __restrict__ rows, int* __restrict__ deg,
                                  int* __restrict__ rank, int E) {
    int e = blockIdx.x * blockDim.x + threadIdx.x;
    if (e < E) rank[e] = atomicAdd(&deg[rows[e]], 1);
}

__global__ void count_kernel(const int* __restrict__ rows, int* __restrict__ deg, int E) {
    int e = blockIdx.x * blockDim.x + threadIdx.x;
    if (e < E) atomicAdd(&deg[rows[e]], 1);
}

__global__ __launch_bounds__(SCAN_B) void scan_p1(const int* __restrict__ deg,
                                                  int* __restrict__ bsums, int N) {
    __shared__ int red[SCAN_B];
    int i = blockIdx.x * SCAN_B + threadIdx.x;
    red[threadIdx.x] = (i < N) ? deg[i] : 0;
    __syncthreads();
    for (int off = SCAN_B / 2; off > 0; off >>= 1) {
        if (threadIdx.x < off) red[threadIdx.x] += red[threadIdx.x + off];
        __syncthreads();
    }
    if (threadIdx.x == 0) bsums[blockIdx.x] = red[0];
}

__global__ __launch_bounds__(SCAN_B) void scan_p2(int* __restrict__ bsums, int B) {
    __shared__ int part[SCAN_B];
    int t = threadIdx.x;
    part[t] = (t < B) ? bsums[t] : 0;
    __syncthreads();
    for (int off = 1; off < SCAN_B; off <<= 1) {
        int v = (t >= off) ? part[t - off] : 0;
        __syncthreads();
        part[t] += v;
        __syncthreads();
    }
    if (t < B) bsums[t] = (t == 0) ? 0 : part[t - 1];   // exclusive
}

template <bool WRITE_CURSOR>
__global__ __launch_bounds__(SCAN_B) void scan_p3_t(int* __restrict__ deg,
                                                    const int* __restrict__ bsums,
                                                    int* __restrict__ offs, int N) {
    __shared__ int part[SCAN_B];
    int t = threadIdx.x;
    int i = blockIdx.x * SCAN_B + t;
    int d = (i < N) ? deg[i] : 0;
    part[t] = d;
    __syncthreads();
    for (int off = 1; off < SCAN_B; off <<= 1) {
        int v = (t >= off) ? part[t - off] : 0;
        __syncthreads();
        part[t] += v;
        __syncthreads();
    }
    int pre = bsums[blockIdx.x] + part[t] - d;
    if (i < N) {
        offs[i] = pre;
        if (WRITE_CURSOR) deg[i] = pre;   // deg becomes cursor
        if (i == N - 1) offs[N] = pre + d;
    }
}

// fill (int8 + XCD-rank path): pos = offs[row] + deg_x_base[xcd][row] + lrank.
// Coefficient folds the column's dequant scale: f' = g(w) * xscale[col].
__global__ __launch_bounds__(256) void fill_rank_q_kernel(
    const int* __restrict__ rows, const int* __restrict__ cols,
    const float* __restrict__ ew, const int* __restrict__ rank,
    const int* __restrict__ offs, const int* __restrict__ deg_x,
    const float* __restrict__ xscale, const float* __restrict__ lut,
    int2* __restrict__ epack, int E, int N) {
    __shared__ float sl[LUTK + 1];
    for (int i = threadIdx.x; i <= LUTK; i += 256) sl[i] = lut[i];
    __syncthreads();
    int e = blockIdx.x * 256 + threadIdx.x;
    if (e >= E) return;
    float f = lut_eval(sl, __builtin_nontemporal_load(&ew[e]));
    int r = __builtin_nontemporal_load(&rows[e]);
    int c = __builtin_nontemporal_load(&cols[e]);
    int pk = __builtin_nontemporal_load(&rank[e]);
    int xcd = ((unsigned)pk) >> 24;
    int lr = pk & 0xffffff;
    float fs = f * xscale[c];
    int pos = offs[r] + deg_x[(size_t)xcd * N + r] + lr;
    epack[pos] = make_int2(c, __float_as_int(fs));
}

// fill (plain rank path, tier B)
__global__ __launch_bounds__(256) void fill_rank_kernel(
    const int* __restrict__ rows, const int* __restrict__ cols,
    const float* __restrict__ ew, const int* __restrict__ rank,
    const int* __restrict__ offs, const float* __restrict__ lut,
    int2* __restrict__ epack, int E) {
    __shared__ float sl[LUTK + 1];
    for (int i = threadIdx.x; i <= LUTK; i += 256) sl[i] = lut[i];
    __syncthreads();
    int e = blockIdx.x * 256 + threadIdx.x;
    if (e >= E) return;
    float f = lut_eval(sl, __builtin_nontemporal_load(&ew[e]));
    int pos = offs[__builtin_nontemporal_load(&rows[e])] +
              __builtin_nontemporal_load(&rank[e]);
    epack[pos] = make_int2(__builtin_nontemporal_load(&cols[e]), __float_as_int(f));
}

// fill (cursor path)
__global__ __launch_bounds__(256) void fill_cursor_kernel(
    const int* __restrict__ rows, const int* __restrict__ cols,
    const float* __restrict__ ew, int* __restrict__ cursor,
    const float* __restrict__ lut, int2* __restrict__ epack, int E) {
    __shared__ float sl[LUTK + 1];
    for (int i = threadIdx.x; i <= LUTK; i += 256) sl[i] = lut[i];
    __syncthreads();
    int e = blockIdx.x * 256 + threadIdx.x;
    if (e >= E) return;
    float f = lut_eval(sl, ew[e]);
    int pos = atomicAdd(&cursor[rows[e]], 1);
    epack[pos] = make_int2(cols[e], __float_as_int(f));
}

// ---------------------------------------------------------------------------
// gather (int8 xq): 16 lanes/node, int2 (8 B = 8 elems)/lane = 128 B per edge
// row (half the bf16 bytes through the L2-miss fabric). Dequant scale is
// pre-folded into f. epack NT-loaded (single-use stream; keeps xq L2-resident).
// ---------------------------------------------------------------------------
__device__ __forceinline__ void qfma8(int lo, int hi, float f, float* a) {
    a[0] = fmaf((float)((int)(((unsigned)lo) << 24) >> 24), f, a[0]);
    a[1] = fmaf((float)((int)(((unsigned)lo) << 16) >> 24), f, a[1]);
    a[2] = fmaf((float)((int)(((unsigned)lo) << 8) >> 24), f, a[2]);
    a[3] = fmaf((float)(lo >> 24), f, a[3]);
    a[4] = fmaf((float)((int)(((unsigned)hi) << 24) >> 24), f, a[4]);
    a[5] = fmaf((float)((int)(((unsigned)hi) << 16) >> 24), f, a[5]);
    a[6] = fmaf((float)((int)(((unsigned)hi) << 8) >> 24), f, a[6]);
    a[7] = fmaf((float)(hi >> 24), f, a[7]);
}

__global__ __launch_bounds__(256) void gather_q8_kernel(const int* __restrict__ offs,
                                                        const int2* __restrict__ epack,
                                                        const signed char* __restrict__ xq,
                                                        short* __restrict__ aggh, int N) {
    int t = threadIdx.x;
    int node = blockIdx.x * 16 + (t >> 4);
    if (node >= N) return;
    int lane = t & 15;
    int s = offs[node], eend = offs[node + 1];
    const signed char* xb = xq + lane * 8;

    float a[8];
    #pragma unroll
    for (int j = 0; j < 8; ++j) a[j] = 0.f;

    int i = s;
    for (; i + 4 <= eend; i += 4) {
        i32x2 p0 = __builtin_nontemporal_load((const i32x2*)&epack[i]);
        i32x2 p1 = __builtin_nontemporal_load((const i32x2*)&epack[i + 1]);
        i32x2 p2 = __builtin_nontemporal_load((const i32x2*)&epack[i + 2]);
        i32x2 p3 = __builtin_nontemporal_load((const i32x2*)&epack[i + 3]);
        int2 q0 = *(const int2*)(xb + (size_t)p0[0] * HIDDEN);
        int2 q1 = *(const int2*)(xb + (size_t)p1[0] * HIDDEN);
        int2 q2 = *(const int2*)(xb + (size_t)p2[0] * HIDDEN);
        int2 q3 = *(const int2*)(xb + (size_t)p3[0] * HIDDEN);
        qfma8(q0.x, q0.y, __int_as_float(p0[1]), a);
        qfma8(q1.x, q1.y, __int_as_float(p1[1]), a);
        qfma8(q2.x, q2.y, __int_as_float(p2[1]), a);
        qfma8(q3.x, q3.y, __int_as_float(p3[1]), a);
    }
    for (; i < eend; ++i) {
        i32x2 p = __builtin_nontemporal_load((const i32x2*)&epack[i]);
        int2 q = *(const int2*)(xb + (size_t)p[0] * HIDDEN);
        qfma8(q.x, q.y, __int_as_float(p[1]), a);
    }

    bf16x8 o;
    #pragma unroll
    for (int j = 0; j < 8; ++j) o[j] = f2bf(a[j]);
    *(bf16x8*)&aggh[(size_t)node * HIDDEN + lane * 8] = o;
}

// fp32 variant (tier B/C)
__global__ __launch_bounds__(256) void gather_kernel(const int* __restrict__ offs,
                                                     const int2* __restrict__ epack,
                                                     const float* __restrict__ x,
                                                     float* __restrict__ agg, int N) {
    int t = threadIdx.x;
    int node = blockIdx.x * 8 + (t >> 5);
    if (node >= N) return;
    int lane = t & 31;
    int s = offs[node], eend = offs[node + 1];
    float4 acc = make_float4(0.f, 0.f, 0.f, 0.f);
    int i = s;
    for (; i + 2 <= eend; i += 2) {
        int2 p0 = epack[i];
        int2 p1 = epack[i + 1];
        float4 x0 = *(const float4*)&x[(size_t)p0.x * HIDDEN + lane * 4];
        float4 x1 = *(const float4*)&x[(size_t)p1.x * HIDDEN + lane * 4];
        float f0 = __int_as_float(p0.y), f1 = __int_as_float(p1.y);
        acc.x = fmaf(x0.x, f0, acc.x); acc.y = fmaf(x0.y, f0, acc.y);
        acc.z = fmaf(x0.z, f0, acc.z); acc.w = fmaf(x0.w, f0, acc.w);
        acc.x = fmaf(x1.x, f1, acc.x); acc.y = fmaf(x1.y, f1, acc.y);
        acc.z = fmaf(x1.z, f1, acc.z); acc.w = fmaf(x1.w, f1, acc.w);
    }
    for (; i < eend; ++i) {
        int2 p = epack[i];
        float f = __int_as_float(p.y);
        const float4 xv = *(const float4*)&x[(size_t)p.x * HIDDEN + lane * 4];
        acc.x = fmaf(xv.x, f, acc.x);
        acc.y = fmaf(xv.y, f, acc.y);
        acc.z = fmaf(xv.z, f, acc.z);
        acc.w = fmaf(xv.w, f, acc.w);
    }
    *(float4*)&agg[(size_t)node * HIDDEN + lane * 4] = acc;
}

// ---------------------------------------------------------------------------
// MFMA MLP (bf16 A from aggh; io fp32 out).
//   out = scf * (softplus(A @ Wi1 + bi1) @ Wi2) + shf
// W staged in LDS (XOR-swizzled, conflict-free ds_read_b128); W2 prefetched
// to regs during phase A; 512-thread / 128-row blocks; NT output stores.
// ---------------------------------------------------------------------------
#define HROW 136   // 128 + 8 shorts pad for the hS activation buffer

// W-tile swizzle: row = byte>>8 (256 B rows); spread 8 rows across 8 16B slots
#define WSWZ(b) ((b) ^ ((((b) >> 8) & 7) << 4))

__global__ __launch_bounds__(512) void mlp_mfma_bf_kernel(
    const short* __restrict__ aggh, float* __restrict__ io,
    const short* __restrict__ W1T, const short* __restrict__ W2T,
    const float* __restrict__ bi1,
    const float* __restrict__ scf, const float* __restrict__ shf,
    int N) {
    __shared__ short wS[HIDDEN * HIDDEN];   // 32 KB  (W1, then W2)
    __shared__ short hS[128 * HROW];        // 34.8 KB activations

    const int t = threadIdx.x;
    const int wave = t >> 6;        // 0..7
    const int lane = t & 63;
    const int quad = lane >> 4;
    const int m16  = lane & 15;
    const int row0 = blockIdx.x * 128 + wave * 16;
    const int arow = row0 + m16;

    const int swzmask = (m16 & 7) << 4;

    // ---- stage W1 -> LDS (swizzled); prefetch W2 into regs (held thru phase A)
    bf16x8 w2r[4];
    {
        const bf16x8* w1v = (const bf16x8*)W1T;
        const bf16x8* w2v = (const bf16x8*)W2T;
        bf16x8 w1r[4];
        #pragma unroll
        for (int j = 0; j < 4; ++j) w1r[j] = w1v[t + 512 * j];
        #pragma unroll
        for (int j = 0; j < 4; ++j) w2r[j] = w2v[t + 512 * j];
        #pragma unroll
        for (int j = 0; j < 4; ++j) {
            int b = (t + 512 * j) * 16;
            *(bf16x8*)((char*)wS + WSWZ(b)) = w1r[j];
        }
    }

    float b1v[8];
    #pragma unroll
    for (int ct = 0; ct < 8; ++ct) b1v[ct] = bi1[ct * 16 + m16];

    f32x4 acc[8];
    #pragma unroll
    for (int ct = 0; ct < 8; ++ct) acc[ct] = (f32x4)(0.f);

    __syncthreads();

    // ---- phase A: acc = aggh @ W1
    #pragma unroll
    for (int ks = 0; ks < 4; ++ks) {
        bf16x8 a;
        if (arow < N) {
            a = *(const bf16x8*)&aggh[(size_t)arow * HIDDEN + ks * 32 + quad * 8];
        } else {
            #pragma unroll
            for (int j = 0; j < 8; ++j) a[j] = 0;
        }
        const char* bbase = (const char*)wS + m16 * 256 + ((ks * 64 + quad * 16) ^ swzmask);
        #pragma unroll
        for (int ct = 0; ct < 8; ++ct) {
            bf16x8 b = *(const bf16x8*)(bbase + ct * 4096);
            acc[ct] = __builtin_amdgcn_mfma_f32_16x16x32_bf16(a, b, acc[ct], 0, 0, 0);
        }
    }

    // ---- epilogue A: +bi1, softplus, bf16 -> hS
    #pragma unroll
    for (int ct = 0; ct < 8; ++ct) {
        int col = ct * 16 + m16;
        #pragma unroll
        for (int r = 0; r < 4; ++r) {
            int lrow = wave * 16 + quad * 4 + r;
            float h = softplus_fast(acc[ct][r] + b1v[ct]);
            hS[lrow * HROW + col] = f2bf(h);
        }
        acc[ct] = (f32x4)(0.f);
    }
    __syncthreads();          // all waves done reading wS(W1) + hS complete

    // ---- stage W2 -> LDS from regs
    #pragma unroll
    for (int j = 0; j < 4; ++j) {
        int b = (t + 512 * j) * 16;
        *(bf16x8*)((char*)wS + WSWZ(b)) = w2r[j];
    }
    __syncthreads();

    float scv[8], shv[8];
    #pragma unroll
    for (int ct = 0; ct < 8; ++ct) {
        scv[ct] = scf[ct * 16 + m16];
        shv[ct] = shf[ct * 16 + m16];
    }

    // ---- phase B: acc = h @ W2
    #pragma unroll
    for (int ks = 0; ks < 4; ++ks) {
        bf16x8 a = *(const bf16x8*)&hS[(wave * 16 + m16) * HROW + ks * 32 + quad * 8];
        const char* bbase = (const char*)wS + m16 * 256 + ((ks * 64 + quad * 16) ^ swzmask);
        #pragma unroll
        for (int ct = 0; ct < 8; ++ct) {
            bf16x8 b = *(const bf16x8*)(bbase + ct * 4096);
            acc[ct] = __builtin_amdgcn_mfma_f32_16x16x32_bf16(a, b, acc[ct], 0, 0, 0);
        }
    }

    // ---- epilogue B: BN (folded) + NT fp32 store (write-once output)
    #pragma unroll
    for (int r = 0; r < 4; ++r) {
        int grow = row0 + quad * 4 + r;
        if (grow < N) {
            float* p = &io[(size_t)grow * HIDDEN + m16];
            #pragma unroll
            for (int ct = 0; ct < 8; ++ct)
                __builtin_nontemporal_store(fmaf(acc[ct][r], scv[ct], shv[ct]), p + ct * 16);
        }
    }
}

// fp32-A variant (tier B/C): in-place on io
__global__ __launch_bounds__(256) void mlp_mfma_kernel(
    float* io,
    const short* __restrict__ W1T, const short* __restrict__ W2T,
    const float* __restrict__ bi1,
    const float* __restrict__ scf, const float* __restrict__ shf,
    int N) {
    __shared__ short hS[64 * HROW];

    const int t = threadIdx.x;
    const int wave = t >> 6;
    const int lane = t & 63;
    const int quad = lane >> 4;
    const int m16  = lane & 15;
    const int row0 = blockIdx.x * 64 + wave * 16;
    const int arow = row0 + m16;

    f32x4 acc[8];
    #pragma unroll
    for (int ct = 0; ct < 8; ++ct) acc[ct] = (f32x4)(0.f);

    #pragma unroll
    for (int ks = 0; ks < 4; ++ks) {
        bf16x8 a;
        if (arow < N) {
            const float* ap = &io[(size_t)arow * HIDDEN + ks * 32 + quad * 8];
            float4 v0 = *(const float4*)ap;
            float4 v1 = *(const float4*)(ap + 4);
            a[0] = f2bf(v0.x); a[1] = f2bf(v0.y); a[2] = f2bf(v0.z); a[3] = f2bf(v0.w);
            a[4] = f2bf(v1.x); a[5] = f2bf(v1.y); a[6] = f2bf(v1.z); a[7] = f2bf(v1.w);
        } else {
            #pragma unroll
            for (int j = 0; j < 8; ++j) a[j] = 0;
        }
        #pragma unroll
        for (int ct = 0; ct < 8; ++ct) {
            bf16x8 b = *(const bf16x8*)&W1T[(ct * 16 + m16) * HIDDEN + ks * 32 + quad * 8];
            acc[ct] = __builtin_amdgcn_mfma_f32_16x16x32_bf16(a, b, acc[ct], 0, 0, 0);
        }
    }

    #pragma unroll
    for (int ct = 0; ct < 8; ++ct) {
        int col = ct * 16 + m16;
        float b1 = bi1[col];
        #pragma unroll
        for (int r = 0; r < 4; ++r) {
            int lrow = wave * 16 + quad * 4 + r;
            float h = softplus_fast(acc[ct][r] + b1);
            hS[lrow * HROW + col] = f2bf(h);
            acc[ct][r] = 0.f;
        }
    }
    __syncthreads();

    #pragma unroll
    for (int ks = 0; ks < 4; ++ks) {
        bf16x8 a = *(const bf16x8*)&hS[(wave * 16 + m16) * HROW + ks * 32 + quad * 8];
        #pragma unroll
        for (int ct = 0; ct < 8; ++ct) {
            bf16x8 b = *(const bf16x8*)&W2T[(ct * 16 + m16) * HIDDEN + ks * 32 + quad * 8];
            acc[ct] = __builtin_amdgcn_mfma_f32_16x16x32_bf16(a, b, acc[ct], 0, 0, 0);
        }
    }

    #pragma unroll
    for (int ct = 0; ct < 8; ++ct) {
        int col = ct * 16 + m16;
        float sc = scf[col], sh = shf[col];
        #pragma unroll
        for (int r = 0; r < 4; ++r) {
            int grow = row0 + quad * 4 + r;
            if (grow < N)
                io[(size_t)grow * HIDDEN + col] = fmaf(acc[ct][r], sc, sh);
        }
    }
}

// ---------------------------------------------------------------------------
// Fallback path kernels (tiny ws): atomic scatter + fp32 vector MLP
// ---------------------------------------------------------------------------
__global__ void edge_filter_kernel(const float* __restrict__ ew,
                                   const float* __restrict__ Wf1, const float* __restrict__ bf1,
                                   const float* __restrict__ wsum, const float* __restrict__ bsum,
                                   float* __restrict__ fs, int E) {
    __shared__ float sW[NFILT], sB[NFILT], sS[NFILT];
    if (threadIdx.x < NFILT) {
        sW[threadIdx.x] = Wf1[threadIdx.x];
        sB[threadIdx.x] = bf1[threadIdx.x];
        sS[threadIdx.x] = wsum[threadIdx.x];
    }
    __syncthreads();
    int e = blockIdx.x * blockDim.x + threadIdx.x;
    if (e >= E) return;
    fs[e] = edge_coeff(ew[e], sW, sB, sS, *bsum);
}

__global__ void scatter_kernel(const int* __restrict__ rows, const int* __restrict__ cols,
                               const float* __restrict__ x, const float* __restrict__ fs,
                               float* __restrict__ agg, int E) {
    int t = threadIdx.x;
    int e = blockIdx.x * 8 + (t >> 5);
    if (e >= E) return;
    int lane = t & 31;
    int r = rows[e];
    int c = cols[e];
    float f = fs[e];
    const float4 xv = *(const float4*)&x[c * HIDDEN + lane * 4];
    float* dst = &agg[r * HIDDEN + lane * 4];
    atomicAdd(dst + 0, xv.x * f);
    atomicAdd(dst + 1, xv.y * f);
    atomicAdd(dst + 2, xv.z * f);
    atomicAdd(dst + 3, xv.w * f);
}

__global__ __launch_bounds__(256) void mlp_kernel(
    float* __restrict__ io,
    const float* __restrict__ Wi1, const float* __restrict__ bi1,
    const float* __restrict__ Wi2, const float* __restrict__ bi2,
    const float* __restrict__ gamma, const float* __restrict__ beta,
    const float* __restrict__ mean, const float* __restrict__ var,
    int N) {
    __shared__ float As[64 * HIDDEN];
    __shared__ float Wh[64 * HIDDEN];

    const int t = threadIdx.x;
    const int row0 = blockIdx.x * 64;
    const int col4 = (t & 31) * 4;
    const int rgrp = t >> 5;

    #pragma unroll
    for (int i = 0; i < 8; ++i) {
        int f4 = t + 256 * i;
        int r = f4 >> 5, c4 = (f4 & 31) * 4;
        int node = row0 + r;
        float4 v = make_float4(0.f, 0.f, 0.f, 0.f);
        if (node < N) v = *(const float4*)&io[node * HIDDEN + c4];
        *(float4*)&As[r * HIDDEN + c4] = v;
    }

    float acc[8][4];
    #pragma unroll
    for (int r = 0; r < 8; ++r)
        for (int j = 0; j < 4; ++j) acc[r][j] = 0.f;

    for (int kh = 0; kh < 2; ++kh) {
        __syncthreads();
        #pragma unroll
        for (int i = 0; i < 8; ++i) {
            int f4 = t + 256 * i;
            int kr = f4 >> 5, c4 = (f4 & 31) * 4;
            *(float4*)&Wh[kr * HIDDEN + c4] = *(const float4*)&Wi1[(kh * 64 + kr) * HIDDEN + c4];
        }
        __syncthreads();
        for (int k = 0; k < 64; ++k) {
            float4 w = *(const float4*)&Wh[k * HIDDEN + col4];
            #pragma unroll
            for (int r = 0; r < 8; ++r) {
                float a = As[(rgrp + 8 * r) * HIDDEN + kh * 64 + k];
                acc[r][0] = fmaf(a, w.x, acc[r][0]);
                acc[r][1] = fmaf(a, w.y, acc[r][1]);
                acc[r][2] = fmaf(a, w.z, acc[r][2]);
                acc[r][3] = fmaf(a, w.w, acc[r][3]);
            }
        }
    }
    __syncthreads();

    {
        float4 b = *(const float4*)&bi1[col4];
        float bv[4] = {b.x, b.y, b.z, b.w};
        #pragma unroll
        for (int r = 0; r < 8; ++r) {
            float hv[4];
            #pragma unroll
            for (int j = 0; j < 4; ++j) {
                float v = acc[r][j] + bv[j];
                hv[j] = softplus_fast(v);
                acc[r][j] = 0.f;
            }
            *(float4*)&As[(rgrp + 8 * r) * HIDDEN + col4] =
                make_float4(hv[0], hv[1], hv[2], hv[3]);
        }
    }

    for (int kh = 0; kh < 2; ++kh) {
        __syncthreads();
        #pragma unroll
        for (int i = 0; i < 8; ++i) {
            int f4 = t + 256 * i;
            int kr = f4 >> 5, c4 = (f4 & 31) * 4;
            *(float4*)&Wh[kr * HIDDEN + c4] = *(const float4*)&Wi2[(kh * 64 + kr) * HIDDEN + c4];
        }
        __syncthreads();
        for (int k = 0; k < 64; ++k) {
            float4 w = *(const float4*)&Wh[k * HIDDEN + col4];
            #pragma unroll
            for (int r = 0; r < 8; ++r) {
                float a = As[(rgrp + 8 * r) * HIDDEN + kh * 64 + k];
                acc[r][0] = fmaf(a, w.x, acc[r][0]);
                acc[r][1] = fmaf(a, w.y, acc[r][1]);
                acc[r][2] = fmaf(a, w.z, acc[r][2]);
                acc[r][3] = fmaf(a, w.w, acc[r][3]);
            }
        }
    }

    {
        float4 b2 = *(const float4*)&bi2[col4];
        float4 g  = *(const float4*)&gamma[col4];
        float4 be = *(const float4*)&beta[col4];
        float4 mu = *(const float4*)&mean[col4];
        float4 va = *(const float4*)&var[col4];
        float bv[4]  = {b2.x, b2.y, b2.z, b2.w};
        float gv[4]  = {g.x, g.y, g.z, g.w};
        float bev[4] = {be.x, be.y, be.z, be.w};
        float muv[4] = {mu.x, mu.y, mu.z, mu.w};
        float vav[4] = {va.x, va.y, va.z, va.w};
        float sc[4];
        #pragma unroll
        for (int j = 0; j < 4; ++j) sc[j] = gv[j] * rsqrtf(vav[j] + 1e-3f);
        #pragma unroll
        for (int r = 0; r < 8; ++r) {
            int node = row0 + rgrp + 8 * r;
            if (node < N) {
                float o[4];
                #pragma unroll
                for (int j = 0; j < 4; ++j)
                    o[j] = (acc[r][j] + bv[j] - muv[j]) * sc[j] + bev[j];
                *(float4*)&io[node * HIDDEN + col4] = make_float4(o[0], o[1], o[2], o[3]);
            }
        }
    }
}

extern "C" void kernel_launch(void* const* d_in, const int* in_sizes, int n_in,
                              void* d_out, int out_size, void* d_ws, size_t ws_size,
                              hipStream_t stream) {
    const float* x    = (const float*)d_in[0];
    const int*   ei   = (const int*)d_in[1];
    const float* ew   = (const float*)d_in[2];
    // d_in[3] = edge_attr: unused by the reference math
    const float* Wf1  = (const float*)d_in[4];
    const float* bf1  = (const float*)d_in[5];
    const float* Wf2  = (const float*)d_in[6];
    const float* bf2  = (const float*)d_in[7];
    const float* Wi1  = (const float*)d_in[8];
    const float* bi1  = (const float*)d_in[9];
    const float* Wi2  = (const float*)d_in[10];
    const float* bi2  = (const float*)d_in[11];
    const float* gam  = (const float*)d_in[12];
    const float* bet  = (const float*)d_in[13];
    const float* mmu  = (const float*)d_in[14];
    const float* mva  = (const float*)d_in[15];

    const int N = in_sizes[0] / HIDDEN;
    const int E = in_sizes[2];
    const int* rows = ei;
    const int* cols = ei + E;

    float* io = (float*)d_out;     // final output; tier B/C also use it as agg

    const int B = (N + SCAN_B - 1) / SCAN_B;

    // ws layout:
    //   deg[N] | offs[N+1] | bsums[B] | wsum[64] | bsum[1] | lut[LUTK+1] | pad |
    //   epack[E] int2 | pad | W1T | W2T | scf[128] | shf[128] | pad |
    //   rank[E] | pad | xq[N*128] int8 | pad | xscale[N] f32 | pad | aggh[N*128] bf16
    //   (deg_x[8*N] aliases the aggh region — dead until gather)
    char* ws = (char*)d_ws;
    int*   deg    = (int*)ws;
    int*   offs   = deg + N;
    int*   bsums  = offs + N + 1;
    float* wsumv  = (float*)(bsums + B);
    float* bsumv  = wsumv + NFILT;
    float* lut    = bsumv + 1;
    size_t hdr_ints  = (size_t)(2 * N + 1 + B + NFILT + 1 + LUTK + 1);
    size_t epack_off = ((hdr_ints * 4) + 15) & ~(size_t)15;
    int2*  epack  = (int2*)(ws + epack_off);
    size_t wT_off = (epack_off + (size_t)E * sizeof(int2) + 15) & ~(size_t)15;
    short* W1T    = (short*)(ws + wT_off);
    short* W2T    = W1T + HIDDEN * HIDDEN;
    float* scf    = (float*)(W2T + HIDDEN * HIDDEN);
    float* shf    = scf + HIDDEN;
    size_t base_need = wT_off + 2 * HIDDEN * HIDDEN * sizeof(short) + 2 * HIDDEN * sizeof(float);
    size_t rank_off  = (base_need + 15) & ~(size_t)15;
    int*   rank   = (int*)(ws + rank_off);
    size_t rank_need = rank_off + (size_t)E * sizeof(int);
    size_t xq_off    = (rank_need + 15) & ~(size_t)15;
    signed char* xq  = (signed char*)(ws + xq_off);
    size_t xs_off    = (xq_off + (size_t)N * HIDDEN + 15) & ~(size_t)15;
    float* xscale    = (float*)(ws + xs_off);
    size_t ag_off    = (xs_off + (size_t)N * sizeof(float) + 15) & ~(size_t)15;
    short* aggh      = (short*)(ws + ag_off);
    int*   deg_x     = (int*)aggh;   // alias: deg_x dead before gather writes aggh
    size_t bf_need   = ag_off + (size_t)N * HIDDEN * sizeof(short);

    if (ws_size >= base_need && B <= SCAN_B) {
        const bool use_rank = (ws_size >= rank_need);
        const bool use_bf   = (ws_size >= bf_need);   // implies use_rank
        if (use_bf) {
            hipMemsetAsync(deg_x, 0, (size_t)NXCD * N * sizeof(int), stream);
        } else {
            hipMemsetAsync(deg, 0, (size_t)N * sizeof(int), stream);
        }
        prep_w_kernel<<<128, 256, 0, stream>>>(Wi1, Wi2, W1T, W2T,
                                               Wf2, bf2, wsumv, bsumv,
                                               bi2, gam, bet, mmu, mva, scf, shf);
        lut_kernel<<<(LUTK + 256) / 256, 256, 0, stream>>>(Wf1, bf1, wsumv, bsumv, lut);
        if (use_bf) {
            int N16 = N * 16;                 // 16 lanes per node row
            int work = (N16 > E) ? N16 : E;
            x2q_count_kernel<<<(work + 255) / 256, 256, 0, stream>>>(x, xq, xscale, N16,
                                                                     rows, deg_x, rank,
                                                                     E, N);
            rowscan8_kernel<<<(N + 255) / 256, 256, 0, stream>>>(deg_x, deg, N);
        } else if (use_rank) {
            count_rank_kernel<<<(E + 255) / 256, 256, 0, stream>>>(rows, deg, rank, E);
        } else {
            count_kernel<<<(E + 255) / 256, 256, 0, stream>>>(rows, deg, E);
        }
        scan_p1<<<B, SCAN_B, 0, stream>>>(deg, bsums, N);
        scan_p2<<<1, SCAN_B, 0, stream>>>(bsums, B);
        if (use_bf) {
            scan_p3_t<false><<<B, SCAN_B, 0, stream>>>(deg, bsums, offs, N);
            fill_rank_q_kernel<<<(E + 255) / 256, 256, 0, stream>>>(rows, cols, ew, rank,
                                                                    offs, deg_x, xscale,
                                                                    lut, epack, E, N);
            gather_q8_kernel<<<(N + 15) / 16, 256, 0, stream>>>(offs, epack, xq, aggh, N);
            mlp_mfma_bf_kernel<<<(N + 127) / 128, 512, 0, stream>>>(aggh, io, W1T, W2T,
                                                                    bi1, scf, shf, N);
        } else if (use_rank) {
            scan_p3_t<false><<<B, SCAN_B, 0, stream>>>(deg, bsums, offs, N);
            fill_rank_kernel<<<(E + 255) / 256, 256, 0, stream>>>(rows, cols, ew, rank,
                                                                  offs, lut, epack, E);
            gather_kernel<<<(N + 7) / 8, 256, 0, stream>>>(offs, epack, x, io, N);
            mlp_mfma_kernel<<<(N + 63) / 64, 256, 0, stream>>>(io, W1T, W2T, bi1, scf, shf, N);
        } else {
            scan_p3_t<true><<<B, SCAN_B, 0, stream>>>(deg, bsums, offs, N);
            fill_cursor_kernel<<<(E + 255) / 256, 256, 0, stream>>>(rows, cols, ew, deg,
                                                                    lut, epack, E);
            gather_kernel<<<(N + 7) / 8, 256, 0, stream>>>(offs, epack, x, io, N);
            mlp_mfma_kernel<<<(N + 63) / 64, 256, 0, stream>>>(io, W1T, W2T, bi1, scf, shf, N);
        }
    } else {
        // ---- fallback: atomic scatter + fp32 MLP ----
        float* fs = (float*)d_ws;             // [E]
        float* w2 = fs + E;                   // [64]
        float* b2 = w2 + NFILT;               // [1]
        hipMemsetAsync(d_out, 0, (size_t)out_size * sizeof(float), stream);
        wsum_kernel<<<1, 64, 0, stream>>>(Wf2, bf2, w2, b2);
        edge_filter_kernel<<<(E + 255) / 256, 256, 0, stream>>>(ew, Wf1, bf1, w2, b2, fs, E);
        scatter_kernel<<<(E + 7) / 8, 256, 0, stream>>>(rows, cols, x, fs, io, E);
        mlp_kernel<<<(N + 63) / 64, 256, 0, stream>>>(io, Wi1, bi1, Wi2, bi2,
                                                      gam, bet, mmu, mva, N);
    }
}

// Round 8
// 351.324 us; speedup vs baseline: 1.0098x; 1.0098x over previous
//
#include <hip/hip_runtime.h>
#include <math.h>

#define HIDDEN 128
#define NFILT 64
#define SCAN_B 1024
#define LUTK 2048   // LUT entries over w in [0,8]; lerp err ~5e-7
#define NXCD 8

typedef __attribute__((ext_vector_type(8))) short bf16x8;
typedef __attribute__((ext_vector_type(4))) float f32x4;
typedef __attribute__((ext_vector_type(4))) float f32x4v;
typedef __attribute__((ext_vector_type(2))) int i32x2;

__device__ __forceinline__ short f2bf(float f) {
    unsigned u = __float_as_uint(f);
    unsigned r = (u + 0x7fffu + ((u >> 16) & 1u)) >> 16;   // RNE
    return (short)r;
}
__device__ __forceinline__ float bf2f(unsigned short u) {
    return __uint_as_float(((unsigned)u) << 16);
}

// physical XCD id (0..7). Wave-uniform; verified working on gfx950 (m09/R7).
__device__ __forceinline__ int xcc_id() {
    int x;
    asm volatile("s_getreg_b32 %0, hwreg(HW_REG_XCC_ID)" : "=s"(x));
    return x & (NXCD - 1);
}

// atomic fetch-add executed in the LOCAL XCD L2: sc0 (return old), NO sc1
// (sc1 would force the memory-side coherence point). Safe here because the
// target line is only ever touched from this XCD (deg_x private copies).
__device__ __forceinline__ int atomic_inc_l2(int* p) {
    int old;
    int one = 1;
    asm volatile("global_atomic_add %0, %1, %2, off sc0\n\t"
                 "s_waitcnt vmcnt(0)"
                 : "=v"(old)
                 : "v"(p), "v"(one)
                 : "memory");
    return old;
}

// softplus via raw v_exp_f32/v_log_f32 (log2 domain): ~5 VALU instrs vs ~25+ for log1pf.
__device__ __forceinline__ float softplus_fast(float v) {
    float e = __builtin_amdgcn_exp2f(v * 1.4426950408889634f);
    float r = 0.69314718055994531f * __builtin_amdgcn_logf(1.0f + e);
    return (v > 80.f) ? v : r;   // exp2 overflow guard
}

// ---------------------------------------------------------------------------
// wsum[j] = sum_f Wf2[j][f]; bsum = sum_f bf2[f]   (fallback path only)
// ---------------------------------------------------------------------------
__global__ void wsum_kernel(const float* __restrict__ Wf2, const float* __restrict__ bf2,
                            float* __restrict__ wsum, float* __restrict__ bsum) {
    int j = threadIdx.x;  // 0..63
    float s = 0.f;
    for (int f = 0; f < NFILT; ++f) s += Wf2[j * NFILT + f];
    wsum[j] = s;
    if (j == 0) {
        float b = 0.f;
        for (int f = 0; f < NFILT; ++f) b += bf2[f];
        *bsum = b;
    }
}

__device__ __forceinline__ float edge_coeff(float w,
                                            const float* sW, const float* sB,
                                            const float* sS, float bsum) {
    float s = fmaf(w, 0.25f, -1.0f);          // w * (2/8) - 1
    float acc = bsum;
    #pragma unroll 8
    for (int j = 0; j < NFILT; ++j)
        acc += tanhf(fmaf(s, sW[j], sB[j])) * sS[j];
    float cut = (w <= 8.0f) ? 0.5f * (cosf(w * 0.39269908169872414f) + 1.0f) : 0.0f;
    return acc * cut;
}

// LUT over the scalar filter function g(w), w in [0,8], LUTK+1 samples
__global__ void lut_kernel(const float* __restrict__ Wf1, const float* __restrict__ bf1,
                           const float* __restrict__ wsum, const float* __restrict__ bsum,
                           float* __restrict__ lut) {
    int i = blockIdx.x * 256 + threadIdx.x;
    if (i > LUTK) return;
    float w = 8.0f * (float)i / (float)LUTK;
    lut[i] = edge_coeff(w, Wf1, bf1, wsum, *bsum);
}

__device__ __forceinline__ float lut_eval(const float* sl, float w) {
    float t = w * ((float)LUTK / 8.0f);
    t = fminf(fmaxf(t, 0.f), (float)LUTK);
    int i = (int)t;
    i = min(i, LUTK - 1);
    return fmaf(t - (float)i, sl[i + 1] - sl[i], sl[i]);
}

// ---------------------------------------------------------------------------
// Prep (fused): W1T/W2T bf16 transpose of Wi1/Wi2 (all blocks);
// block 0: wsum/bsum; block 1: BN fold; all blocks: grid-stride zero of zbuf
// (replaces the deg_x memset dispatch).
// ---------------------------------------------------------------------------
__global__ void prep_w_kernel(const float* __restrict__ Wi1, const float* __restrict__ Wi2,
                              short* __restrict__ W1T, short* __restrict__ W2T,
                              const float* __restrict__ Wf2, const float* __restrict__ bf2,
                              float* __restrict__ wsum, float* __restrict__ bsum,
                              const float* __restrict__ bi2,
                              const float* __restrict__ gamma, const float* __restrict__ beta,
                              const float* __restrict__ mean, const float* __restrict__ var,
                              float* __restrict__ scf, float* __restrict__ shf,
                              int* __restrict__ zbuf, int zn) {
    int idx = blockIdx.x * 256 + threadIdx.x;   // 0..32767
    const float* src = (idx < 16384) ? Wi1 : Wi2;
    short* dst = (idx < 16384) ? W1T : W2T;
    int i = idx & 16383;
    int k = i >> 7, n = i & 127;
    dst[n * HIDDEN + k] = f2bf(src[i]);

    // zero deg_x (grid-stride, int4)
    for (int z = idx; z * 4 < zn; z += 32768) {
        if (z * 4 + 3 < zn) *(int4*)&zbuf[z * 4] = make_int4(0, 0, 0, 0);
        else for (int q = z * 4; q < zn; ++q) zbuf[q] = 0;
    }

    if (blockIdx.x == 0 && threadIdx.x < 64) {
        int j = threadIdx.x;
        float s = 0.f;
        for (int f = 0; f < NFILT; ++f) s += Wf2[j * NFILT + f];
        wsum[j] = s;
        if (j == 0) {
            float b = 0.f;
            for (int f = 0; f < NFILT; ++f) b += bf2[f];
            *bsum = b;
        }
    }
    if (blockIdx.x == 1 && threadIdx.x < HIDDEN) {
        int j = threadIdx.x;
        float sc = gamma[j] * rsqrtf(var[j] + 1e-3f);
        scf[j] = sc;
        shf[j] = (bi2[j] - mean[j]) * sc + beta[j];
    }
}

// ---------------------------------------------------------------------------
// Fused: x fp32 -> xq int8 per-row-scaled (streaming, NT reads) + XCD-local
// CSR count/rank. deg_x[xcd][N]: copy k only touched from physical XCD k;
// the inline-asm atomic (sc0, no sc1) executes the RMW in XCD k's own L2.
// rank packs (xcd<<24)|localrank; end-of-kernel L2 writeback publishes deg_x.
// ---------------------------------------------------------------------------
__global__ __launch_bounds__(256) void x2q_count_kernel(
    const float* __restrict__ x, signed char* __restrict__ xq,
    float* __restrict__ xscale, int N16,
    const int* __restrict__ rows, int* __restrict__ deg_x,
    int* __restrict__ rank, int E, int N) {
    int i = blockIdx.x * 256 + threadIdx.x;
    if (i < E) {
        int r = rows[i];
        int xcd = xcc_id();
        int lr = atomic_inc_l2(&deg_x[(size_t)xcd * N + r]);
        rank[i] = (xcd << 24) | lr;
    }
    if (i < N16) {
        int node = i >> 4, lane = i & 15;
        const float* xp = &x[(size_t)node * HIDDEN + lane * 8];
        const f32x4v v0 = __builtin_nontemporal_load((const f32x4v*)xp);
        const f32x4v v1 = __builtin_nontemporal_load((const f32x4v*)(xp + 4));
        float v[8] = {v0[0], v0[1], v0[2], v0[3], v1[0], v1[1], v1[2], v1[3]};
        float m = 0.f;
        #pragma unroll
        for (int j = 0; j < 8; ++j) m = fmaxf(m, fabsf(v[j]));
        // reduce max across the 16 lanes of this node
        #pragma unroll
        for (int off = 8; off > 0; off >>= 1)
            m = fmaxf(m, __shfl_xor(m, off, 16));
        float si = (m > 0.f) ? 127.f / m : 0.f;
        int q[8];
        #pragma unroll
        for (int j = 0; j < 8; ++j) q[j] = __float2int_rn(v[j] * si);
        int lo = (q[0] & 0xff) | ((q[1] & 0xff) << 8) |
                 ((q[2] & 0xff) << 16) | ((q[3] & 0xff) << 24);
        int hi = (q[4] & 0xff) | ((q[5] & 0xff) << 8) |
                 ((q[6] & 0xff) << 16) | ((q[7] & 0xff) << 24);
        *(int2*)&xq[(size_t)node * HIDDEN + lane * 8] = make_int2(lo, hi);
        if (lane == 0) xscale[node] = m * (1.f / 127.f);
    }
}

// per-row exclusive scan over the 8 XCD copies; bases written back in place,
// total -> deg.
__global__ __launch_bounds__(256) void rowscan8_kernel(int* __restrict__ deg_x,
                                                       int* __restrict__ deg, int N) {
    int r = blockIdx.x * 256 + threadIdx.x;
    if (r >= N) return;
    int s = 0;
    #pragma unroll
    for (int c = 0; c < NXCD; ++c) {
        int v = deg_x[(size_t)c * N + r];
        deg_x[(size_t)c * N + r] = s;
        s += v;
    }
    deg[r] = s;
}

// non-fused variants (tier B path)
__global__ void count_rank_kernel(const int* __restrict__ rows, int* __restrict__ deg,
                                  int* __restrict__ rank, int E) {
    int e = blockIdx.x * blockDim.x + threadIdx.x;
    if (e < E) rank[e] = atomicAdd(&deg[rows[e]], 1);
}

__global__ void count_kernel(const int* __restrict__ rows, int* __restrict__ deg, int E) {
    int e = blockIdx.x * blockDim.x + threadIdx.x;
    if (e < E) atomicAdd(&deg[rows[e]], 1);
}

__global__ __launch_bounds__(SCAN_B) void scan_p1(const int* __restrict__ deg,
                                                  int* __restrict__ bsums, int N) {
    __shared__ int red[SCAN_B];
    int i = blockIdx.x * SCAN_B + threadIdx.x;
    red[threadIdx.x] = (i < N) ? deg[i] : 0;
    __syncthreads();
    for (int off = SCAN_B / 2; off > 0; off >>= 1) {
        if (threadIdx.x < off) red[threadIdx.x] += red[threadIdx.x + off];
        __syncthreads();
    }
    if (threadIdx.x == 0) bsums[blockIdx.x] = red[0];
}

__global__ __launch_bounds__(SCAN_B) void scan_p2(int* __restrict__ bsums, int B) {
    __shared__ int part[SCAN_B];
    int t = threadIdx.x;
    part[t] = (t < B) ? bsums[t] : 0;
    __syncthreads();
    for (int off = 1; off < SCAN_B; off <<= 1) {
        int v = (t >= off) ? part[t - off] : 0;
        __syncthreads();
        part[t] += v;
        __syncthreads();
    }
    if (t < B) bsums[t] = (t == 0) ? 0 : part[t - 1];   // exclusive
}

template <bool WRITE_CURSOR>
__global__ __launch_bounds__(SCAN_B) void scan_p3_t(int* __restrict__ deg,
                                                    const int* __restrict__ bsums,
                                                    int* __restrict__ offs, int N) {
    __shared__ int part[SCAN_B];
    int t = threadIdx.x;
    int i = blockIdx.x * SCAN_B + t;
    int d = (i < N) ? deg[i] : 0;
    part[t] = d;
    __syncthreads();
    for (int off = 1; off < SCAN_B; off <<= 1) {
        int v = (t >= off) ? part[t - off] : 0;
        __syncthreads();
        part[t] += v;
        __syncthreads();
    }
    int pre = bsums[blockIdx.x] + part[t] - d;
    if (i < N) {
        offs[i] = pre;
        if (WRITE_CURSOR) deg[i] = pre;   // deg becomes cursor
        if (i == N - 1) offs[N] = pre + d;
    }
}

// fill (int8 + XCD-rank path): pos = offs[row] + deg_x_base[xcd][row] + lrank.
// Coefficient folds the column's dequant scale: f' = g(w) * xscale[col].
__global__ __launch_bounds__(256) void fill_rank_q_kernel(
    const int* __restrict__ rows, const int* __restrict__ cols,
    const float* __restrict__ ew, const int* __restrict__ rank,
    const int* __restrict__ offs, const int* __restrict__ deg_x,
    const float* __restrict__ xscale, const float* __restrict__ lut,
    int2* __restrict__ epack, int E, int N) {
    __shared__ float sl[LUTK + 1];
    for (int i = threadIdx.x; i <= LUTK; i += 256) sl[i] = lut[i];
    __syncthreads();
    int e = blockIdx.x * 256 + threadIdx.x;
    if (e >= E) return;
    float f = lut_eval(sl, __builtin_nontemporal_load(&ew[e]));
    int r = __builtin_nontemporal_load(&rows[e]);
    int c = __builtin_nontemporal_load(&cols[e]);
    int pk = __builtin_nontemporal_load(&rank[e]);
    int xcd = ((unsigned)pk) >> 24;
    int lr = pk & 0xffffff;
    float fs = f * xscale[c];
    int pos = offs[r] + deg_x[(size_t)xcd * N + r] + lr;
    epack[pos] = make_int2(c, __float_as_int(fs));
}

// fill (plain rank path, tier B)
__global__ __launch_bounds__(256) void fill_rank_kernel(
    const int* __restrict__ rows, const int* __restrict__ cols,
    const float* __restrict__ ew, const int* __restrict__ rank,
    const int* __restrict__ offs, const float* __restrict__ lut,
    int2* __restrict__ epack, int E) {
    __shared__ float sl[LUTK + 1];
    for (int i = threadIdx.x; i <= LUTK; i += 256) sl[i] = lut[i];
    __syncthreads();
    int e = blockIdx.x * 256 + threadIdx.x;
    if (e >= E) return;
    float f = lut_eval(sl, __builtin_nontemporal_load(&ew[e]));
    int pos = offs[__builtin_nontemporal_load(&rows[e])] +
              __builtin_nontemporal_load(&rank[e]);
    epack[pos] = make_int2(__builtin_nontemporal_load(&cols[e]), __float_as_int(f));
}

// fill (cursor path)
__global__ __launch_bounds__(256) void fill_cursor_kernel(
    const int* __restrict__ rows, const int* __restrict__ cols,
    const float* __restrict__ ew, int* __restrict__ cursor,
    const float* __restrict__ lut, int2* __restrict__ epack, int E) {
    __shared__ float sl[LUTK + 1];
    for (int i = threadIdx.x; i <= LUTK; i += 256) sl[i] = lut[i];
    __syncthreads();
    int e = blockIdx.x * 256 + threadIdx.x;
    if (e >= E) return;
    float f = lut_eval(sl, ew[e]);
    int pos = atomicAdd(&cursor[rows[e]], 1);
    epack[pos] = make_int2(cols[e], __float_as_int(f));
}

// ---------------------------------------------------------------------------
// gather (int8 xq): 16 lanes/node, int2 (8 B = 8 elems)/lane = 128 B per edge
// row (half the bf16 bytes through the L2-miss fabric). Dequant scale is
// pre-folded into f. epack NT-loaded (single-use stream; keeps xq L2-resident).
// ---------------------------------------------------------------------------
__device__ __forceinline__ void qfma8(int lo, int hi, float f, float* a) {
    a[0] = fmaf((float)((int)(((unsigned)lo) << 24) >> 24), f, a[0]);
    a[1] = fmaf((float)((int)(((unsigned)lo) << 16) >> 24), f, a[1]);
    a[2] = fmaf((float)((int)(((unsigned)lo) << 8) >> 24), f, a[2]);
    a[3] = fmaf((float)(lo >> 24), f, a[3]);
    a[4] = fmaf((float)((int)(((unsigned)hi) << 24) >> 24), f, a[4]);
    a[5] = fmaf((float)((int)(((unsigned)hi) << 16) >> 24), f, a[5]);
    a[6] = fmaf((float)((int)(((unsigned)hi) << 8) >> 24), f, a[6]);
    a[7] = fmaf((float)(hi >> 24), f, a[7]);
}

__global__ __launch_bounds__(256) void gather_q8_kernel(const int* __restrict__ offs,
                                                        const int2* __restrict__ epack,
                                                        const signed char* __restrict__ xq,
                                                        short* __restrict__ aggh, int N) {
    int t = threadIdx.x;
    int node = blockIdx.x * 16 + (t >> 4);
    if (node >= N) return;
    int lane = t & 15;
    int s = offs[node], eend = offs[node + 1];
    const signed char* xb = xq + lane * 8;

    float a[8];
    #pragma unroll
    for (int j = 0; j < 8; ++j) a[j] = 0.f;

    int i = s;
    for (; i + 4 <= eend; i += 4) {
        i32x2 p0 = __builtin_nontemporal_load((const i32x2*)&epack[i]);
        i32x2 p1 = __builtin_nontemporal_load((const i32x2*)&epack[i + 1]);
        i32x2 p2 = __builtin_nontemporal_load((const i32x2*)&epack[i + 2]);
        i32x2 p3 = __builtin_nontemporal_load((const i32x2*)&epack[i + 3]);
        int2 q0 = *(const int2*)(xb + (size_t)p0[0] * HIDDEN);
        int2 q1 = *(const int2*)(xb + (size_t)p1[0] * HIDDEN);
        int2 q2 = *(const int2*)(xb + (size_t)p2[0] * HIDDEN);
        int2 q3 = *(const int2*)(xb + (size_t)p3[0] * HIDDEN);
        qfma8(q0.x, q0.y, __int_as_float(p0[1]), a);
        qfma8(q1.x, q1.y, __int_as_float(p1[1]), a);
        qfma8(q2.x, q2.y, __int_as_float(p2[1]), a);
        qfma8(q3.x, q3.y, __int_as_float(p3[1]), a);
    }
    for (; i < eend; ++i) {
        i32x2 p = __builtin_nontemporal_load((const i32x2*)&epack[i]);
        int2 q = *(const int2*)(xb + (size_t)p[0] * HIDDEN);
        qfma8(q.x, q.y, __int_as_float(p[1]), a);
    }

    bf16x8 o;
    #pragma unroll
    for (int j = 0; j < 8; ++j) o[j] = f2bf(a[j]);
    *(bf16x8*)&aggh[(size_t)node * HIDDEN + lane * 8] = o;
}

// fp32 variant (tier B/C)
__global__ __launch_bounds__(256) void gather_kernel(const int* __restrict__ offs,
                                                     const int2* __restrict__ epack,
                                                     const float* __restrict__ x,
                                                     float* __restrict__ agg, int N) {
    int t = threadIdx.x;
    int node = blockIdx.x * 8 + (t >> 5);
    if (node >= N) return;
    int lane = t & 31;
    int s = offs[node], eend = offs[node + 1];
    float4 acc = make_float4(0.f, 0.f, 0.f, 0.f);
    int i = s;
    for (; i + 2 <= eend; i += 2) {
        int2 p0 = epack[i];
        int2 p1 = epack[i + 1];
        float4 x0 = *(const float4*)&x[(size_t)p0.x * HIDDEN + lane * 4];
        float4 x1 = *(const float4*)&x[(size_t)p1.x * HIDDEN + lane * 4];
        float f0 = __int_as_float(p0.y), f1 = __int_as_float(p1.y);
        acc.x = fmaf(x0.x, f0, acc.x); acc.y = fmaf(x0.y, f0, acc.y);
        acc.z = fmaf(x0.z, f0, acc.z); acc.w = fmaf(x0.w, f0, acc.w);
        acc.x = fmaf(x1.x, f1, acc.x); acc.y = fmaf(x1.y, f1, acc.y);
        acc.z = fmaf(x1.z, f1, acc.z); acc.w = fmaf(x1.w, f1, acc.w);
    }
    for (; i < eend; ++i) {
        int2 p = epack[i];
        float f = __int_as_float(p.y);
        const float4 xv = *(const float4*)&x[(size_t)p.x * HIDDEN + lane * 4];
        acc.x = fmaf(xv.x, f, acc.x);
        acc.y = fmaf(xv.y, f, acc.y);
        acc.z = fmaf(xv.z, f, acc.z);
        acc.w = fmaf(xv.w, f, acc.w);
    }
    *(float4*)&agg[(size_t)node * HIDDEN + lane * 4] = acc;
}

// ---------------------------------------------------------------------------
// MFMA MLP (bf16 A from aggh; io fp32 out).
//   out = scf * (softplus(A @ Wi1 + bi1) @ Wi2) + shf
// W staged in LDS (XOR-swizzled, conflict-free ds_read_b128); W2 prefetched
// to regs during phase A; 512-thread / 128-row blocks; NT output stores.
// ---------------------------------------------------------------------------
#define HROW 136   // 128 + 8 shorts pad for the hS activation buffer

// W-tile swizzle: row = byte>>8 (256 B rows); spread 8 rows across 8 16B slots
#define WSWZ(b) ((b) ^ ((((b) >> 8) & 7) << 4))

__global__ __launch_bounds__(512) void mlp_mfma_bf_kernel(
    const short* __restrict__ aggh, float* __restrict__ io,
    const short* __restrict__ W1T, const short* __restrict__ W2T,
    const float* __restrict__ bi1,
    const float* __restrict__ scf, const float* __restrict__ shf,
    int N) {
    __shared__ short wS[HIDDEN * HIDDEN];   // 32 KB  (W1, then W2)
    __shared__ short hS[128 * HROW];        // 34.8 KB activations

    const int t = threadIdx.x;
    const int wave = t >> 6;        // 0..7
    const int lane = t & 63;
    const int quad = lane >> 4;
    const int m16  = lane & 15;
    const int row0 = blockIdx.x * 128 + wave * 16;
    const int arow = row0 + m16;

    const int swzmask = (m16 & 7) << 4;

    // ---- stage W1 -> LDS (swizzled); prefetch W2 into regs (held thru phase A)
    bf16x8 w2r[4];
    {
        const bf16x8* w1v = (const bf16x8*)W1T;
        const bf16x8* w2v = (const bf16x8*)W2T;
        bf16x8 w1r[4];
        #pragma unroll
        for (int j = 0; j < 4; ++j) w1r[j] = w1v[t + 512 * j];
        #pragma unroll
        for (int j = 0; j < 4; ++j) w2r[j] = w2v[t + 512 * j];
        #pragma unroll
        for (int j = 0; j < 4; ++j) {
            int b = (t + 512 * j) * 16;
            *(bf16x8*)((char*)wS + WSWZ(b)) = w1r[j];
        }
    }

    float b1v[8];
    #pragma unroll
    for (int ct = 0; ct < 8; ++ct) b1v[ct] = bi1[ct * 16 + m16];

    f32x4 acc[8];
    #pragma unroll
    for (int ct = 0; ct < 8; ++ct) acc[ct] = (f32x4)(0.f);

    __syncthreads();

    // ---- phase A: acc = aggh @ W1
    #pragma unroll
    for (int ks = 0; ks < 4; ++ks) {
        bf16x8 a;
        if (arow < N) {
            a = *(const bf16x8*)&aggh[(size_t)arow * HIDDEN + ks * 32 + quad * 8];
        } else {
            #pragma unroll
            for (int j = 0; j < 8; ++j) a[j] = 0;
        }
        const char* bbase = (const char*)wS + m16 * 256 + ((ks * 64 + quad * 16) ^ swzmask);
        #pragma unroll
        for (int ct = 0; ct < 8; ++ct) {
            bf16x8 b = *(const bf16x8*)(bbase + ct * 4096);
            acc[ct] = __builtin_amdgcn_mfma_f32_16x16x32_bf16(a, b, acc[ct], 0, 0, 0);
        }
    }

    // ---- epilogue A: +bi1, softplus, bf16 -> hS
    #pragma unroll
    for (int ct = 0; ct < 8; ++ct) {
        int col = ct * 16 + m16;
        #pragma unroll
        for (int r = 0; r < 4; ++r) {
            int lrow = wave * 16 + quad * 4 + r;
            float h = softplus_fast(acc[ct][r] + b1v[ct]);
            hS[lrow * HROW + col] = f2bf(h);
        }
        acc[ct] = (f32x4)(0.f);
    }
    __syncthreads();          // all waves done reading wS(W1) + hS complete

    // ---- stage W2 -> LDS from regs
    #pragma unroll
    for (int j = 0; j < 4; ++j) {
        int b = (t + 512 * j) * 16;
        *(bf16x8*)((char*)wS + WSWZ(b)) = w2r[j];
    }
    __syncthreads();

    float scv[8], shv[8];
    #pragma unroll
    for (int ct = 0; ct < 8; ++ct) {
        scv[ct] = scf[ct * 16 + m16];
        shv[ct] = shf[ct * 16 + m16];
    }

    // ---- phase B: acc = h @ W2
    #pragma unroll
    for (int ks = 0; ks < 4; ++ks) {
        bf16x8 a = *(const bf16x8*)&hS[(wave * 16 + m16) * HROW + ks * 32 + quad * 8];
        const char* bbase = (const char*)wS + m16 * 256 + ((ks * 64 + quad * 16) ^ swzmask);
        #pragma unroll
        for (int ct = 0; ct < 8; ++ct) {
            bf16x8 b = *(const bf16x8*)(bbase + ct * 4096);
            acc[ct] = __builtin_amdgcn_mfma_f32_16x16x32_bf16(a, b, acc[ct], 0, 0, 0);
        }
    }

    // ---- epilogue B: BN (folded) + NT fp32 store (write-once output)
    #pragma unroll
    for (int r = 0; r < 4; ++r) {
        int grow = row0 + quad * 4 + r;
        if (grow < N) {
            float* p = &io[(size_t)grow * HIDDEN + m16];
            #pragma unroll
            for (int ct = 0; ct < 8; ++ct)
                __builtin_nontemporal_store(fmaf(acc[ct][r], scv[ct], shv[ct]), p + ct * 16);
        }
    }
}

// fp32-A variant (tier B/C): in-place on io
__global__ __launch_bounds__(256) void mlp_mfma_kernel(
    float* io,
    const short* __restrict__ W1T, const short* __restrict__ W2T,
    const float* __restrict__ bi1,
    const float* __restrict__ scf, const float* __restrict__ shf,
    int N) {
    __shared__ short hS[64 * HROW];

    const int t = threadIdx.x;
    const int wave = t >> 6;
    const int lane = t & 63;
    const int quad = lane >> 4;
    const int m16  = lane & 15;
    const int row0 = blockIdx.x * 64 + wave * 16;
    const int arow = row0 + m16;

    f32x4 acc[8];
    #pragma unroll
    for (int ct = 0; ct < 8; ++ct) acc[ct] = (f32x4)(0.f);

    #pragma unroll
    for (int ks = 0; ks < 4; ++ks) {
        bf16x8 a;
        if (arow < N) {
            const float* ap = &io[(size_t)arow * HIDDEN + ks * 32 + quad * 8];
            float4 v0 = *(const float4*)ap;
            float4 v1 = *(const float4*)(ap + 4);
            a[0] = f2bf(v0.x); a[1] = f2bf(v0.y); a[2] = f2bf(v0.z); a[3] = f2bf(v0.w);
            a[4] = f2bf(v1.x); a[5] = f2bf(v1.y); a[6] = f2bf(v1.z); a[7] = f2bf(v1.w);
        } else {
            #pragma unroll
            for (int j = 0; j < 8; ++j) a[j] = 0;
        }
        #pragma unroll
        for (int ct = 0; ct < 8; ++ct) {
            bf16x8 b = *(const bf16x8*)&W1T[(ct * 16 + m16) * HIDDEN + ks * 32 + quad * 8];
            acc[ct] = __builtin_amdgcn_mfma_f32_16x16x32_bf16(a, b, acc[ct], 0, 0, 0);
        }
    }

    #pragma unroll
    for (int ct = 0; ct < 8; ++ct) {
        int col = ct * 16 + m16;
        float b1 = bi1[col];
        #pragma unroll
        for (int r = 0; r < 4; ++r) {
            int lrow = wave * 16 + quad * 4 + r;
            float h = softplus_fast(acc[ct][r] + b1);
            hS[lrow * HROW + col] = f2bf(h);
            acc[ct][r] = 0.f;
        }
    }
    __syncthreads();

    #pragma unroll
    for (int ks = 0; ks < 4; ++ks) {
        bf16x8 a = *(const bf16x8*)&hS[(wave * 16 + m16) * HROW + ks * 32 + quad * 8];
        #pragma unroll
        for (int ct = 0; ct < 8; ++ct) {
            bf16x8 b = *(const bf16x8*)&W2T[(ct * 16 + m16) * HIDDEN + ks * 32 + quad * 8];
            acc[ct] = __builtin_amdgcn_mfma_f32_16x16x32_bf16(a, b, acc[ct], 0, 0, 0);
        }
    }

    #pragma unroll
    for (int ct = 0; ct < 8; ++ct) {
        int col = ct * 16 + m16;
        float sc = scf[col], sh = shf[col];
        #pragma unroll
        for (int r = 0; r < 4; ++r) {
            int grow = row0 + quad * 4 + r;
            if (grow < N)
                io[(size_t)grow * HIDDEN + col] = fmaf(acc[ct][r], sc, sh);
        }
    }
}

// ---------------------------------------------------------------------------
// Fallback path kernels (tiny ws): atomic scatter + fp32 vector MLP
// ---------------------------------------------------------------------------
__global__ void edge_filter_kernel(const float* __restrict__ ew,
                                   const float* __restrict__ Wf1, const float* __restrict__ bf1,
                                   const float* __restrict__ wsum, const float* __restrict__ bsum,
                                   float* __restrict__ fs, int E) {
    __shared__ float sW[NFILT], sB[NFILT], sS[NFILT];
    if (threadIdx.x < NFILT) {
        sW[threadIdx.x] = Wf1[threadIdx.x];
        sB[threadIdx.x] = bf1[threadIdx.x];
        sS[threadIdx.x] = wsum[threadIdx.x];
    }
    __syncthreads();
    int e = blockIdx.x * blockDim.x + threadIdx.x;
    if (e >= E) return;
    fs[e] = edge_coeff(ew[e], sW, sB, sS, *bsum);
}

__global__ void scatter_kernel(const int* __restrict__ rows, const int* __restrict__ cols,
                               const float* __restrict__ x, const float* __restrict__ fs,
                               float* __restrict__ agg, int E) {
    int t = threadIdx.x;
    int e = blockIdx.x * 8 + (t >> 5);
    if (e >= E) return;
    int lane = t & 31;
    int r = rows[e];
    int c = cols[e];
    float f = fs[e];
    const float4 xv = *(const float4*)&x[c * HIDDEN + lane * 4];
    float* dst = &agg[r * HIDDEN + lane * 4];
    atomicAdd(dst + 0, xv.x * f);
    atomicAdd(dst + 1, xv.y * f);
    atomicAdd(dst + 2, xv.z * f);
    atomicAdd(dst + 3, xv.w * f);
}

__global__ __launch_bounds__(256) void mlp_kernel(
    float* __restrict__ io,
    const float* __restrict__ Wi1, const float* __restrict__ bi1,
    const float* __restrict__ Wi2, const float* __restrict__ bi2,
    const float* __restrict__ gamma, const float* __restrict__ beta,
    const float* __restrict__ mean, const float* __restrict__ var,
    int N) {
    __shared__ float As[64 * HIDDEN];
    __shared__ float Wh[64 * HIDDEN];

    const int t = threadIdx.x;
    const int row0 = blockIdx.x * 64;
    const int col4 = (t & 31) * 4;
    const int rgrp = t >> 5;

    #pragma unroll
    for (int i = 0; i < 8; ++i) {
        int f4 = t + 256 * i;
        int r = f4 >> 5, c4 = (f4 & 31) * 4;
        int node = row0 + r;
        float4 v = make_float4(0.f, 0.f, 0.f, 0.f);
        if (node < N) v = *(const float4*)&io[node * HIDDEN + c4];
        *(float4*)&As[r * HIDDEN + c4] = v;
    }

    float acc[8][4];
    #pragma unroll
    for (int r = 0; r < 8; ++r)
        for (int j = 0; j < 4; ++j) acc[r][j] = 0.f;

    for (int kh = 0; kh < 2; ++kh) {
        __syncthreads();
        #pragma unroll
        for (int i = 0; i < 8; ++i) {
            int f4 = t + 256 * i;
            int kr = f4 >> 5, c4 = (f4 & 31) * 4;
            *(float4*)&Wh[kr * HIDDEN + c4] = *(const float4*)&Wi1[(kh * 64 + kr) * HIDDEN + c4];
        }
        __syncthreads();
        for (int k = 0; k < 64; ++k) {
            float4 w = *(const float4*)&Wh[k * HIDDEN + col4];
            #pragma unroll
            for (int r = 0; r < 8; ++r) {
                float a = As[(rgrp + 8 * r) * HIDDEN + kh * 64 + k];
                acc[r][0] = fmaf(a, w.x, acc[r][0]);
                acc[r][1] = fmaf(a, w.y, acc[r][1]);
                acc[r][2] = fmaf(a, w.z, acc[r][2]);
                acc[r][3] = fmaf(a, w.w, acc[r][3]);
            }
        }
    }
    __syncthreads();

    {
        float4 b = *(const float4*)&bi1[col4];
        float bv[4] = {b.x, b.y, b.z, b.w};
        #pragma unroll
        for (int r = 0; r < 8; ++r) {
            float hv[4];
            #pragma unroll
            for (int j = 0; j < 4; ++j) {
                float v = acc[r][j] + bv[j];
                hv[j] = softplus_fast(v);
                acc[r][j] = 0.f;
            }
            *(float4*)&As[(rgrp + 8 * r) * HIDDEN + col4] =
                make_float4(hv[0], hv[1], hv[2], hv[3]);
        }
    }

    for (int kh = 0; kh < 2; ++kh) {
        __syncthreads();
        #pragma unroll
        for (int i = 0; i < 8; ++i) {
            int f4 = t + 256 * i;
            int kr = f4 >> 5, c4 = (f4 & 31) * 4;
            *(float4*)&Wh[kr * HIDDEN + c4] = *(const float4*)&Wi2[(kh * 64 + kr) * HIDDEN + c4];
        }
        __syncthreads();
        for (int k = 0; k < 64; ++k) {
            float4 w = *(const float4*)&Wh[k * HIDDEN + col4];
            #pragma unroll
            for (int r = 0; r < 8; ++r) {
                float a = As[(rgrp + 8 * r) * HIDDEN + kh * 64 + k];
                acc[r][0] = fmaf(a, w.x, acc[r][0]);
                acc[r][1] = fmaf(a, w.y, acc[r][1]);
                acc[r][2] = fmaf(a, w.z, acc[r][2]);
                acc[r][3] = fmaf(a, w.w, acc[r][3]);
            }
        }
    }

    {
        float4 b2 = *(const float4*)&bi2[col4];
        float4 g  = *(const float4*)&gamma[col4];
        float4 be = *(const float4*)&beta[col4];
        float4 mu = *(const float4*)&mean[col4];
        float4 va = *(const float4*)&var[col4];
        float bv[4]  = {b2.x, b2.y, b2.z, b2.w};
        float gv[4]  = {g.x, g.y, g.z, g.w};
        float bev[4] = {be.x, be.y, be.z, be.w};
        float muv[4] = {mu.x, mu.y, mu.z, mu.w};
        float vav[4] = {va.x, va.y, va.z, va.w};
        float sc[4];
        #pragma unroll
        for (int j = 0; j < 4; ++j) sc[j] = gv[j] * rsqrtf(vav[j] + 1e-3f);
        #pragma unroll
        for (int r = 0; r < 8; ++r) {
            int node = row0 + rgrp + 8 * r;
            if (node < N) {
                float o[4];
                #pragma unroll
                for (int j = 0; j < 4; ++j)
                    o[j] = (acc[r][j] + bv[j] - muv[j]) * sc[j] + bev[j];
                *(float4*)&io[node * HIDDEN + col4] = make_float4(o[0], o[1], o[2], o[3]);
            }
        }
    }
}

extern "C" void kernel_launch(void* const* d_in, const int* in_sizes, int n_in,
                              void* d_out, int out_size, void* d_ws, size_t ws_size,
                              hipStream_t stream) {
    const float* x    = (const float*)d_in[0];
    const int*   ei   = (const int*)d_in[1];
    const float* ew   = (const float*)d_in[2];
    // d_in[3] = edge_attr: unused by the reference math
    const float* Wf1  = (const float*)d_in[4];
    const float* bf1  = (const float*)d_in[5];
    const float* Wf2  = (const float*)d_in[6];
    const float* bf2  = (const float*)d_in[7];
    const float* Wi1  = (const float*)d_in[8];
    const float* bi1  = (const float*)d_in[9];
    const float* Wi2  = (const float*)d_in[10];
    const float* bi2  = (const float*)d_in[11];
    const float* gam  = (const float*)d_in[12];
    const float* bet  = (const float*)d_in[13];
    const float* mmu  = (const float*)d_in[14];
    const float* mva  = (const float*)d_in[15];

    const int N = in_sizes[0] / HIDDEN;
    const int E = in_sizes[2];
    const int* rows = ei;
    const int* cols = ei + E;

    float* io = (float*)d_out;     // final output; tier B/C also use it as agg

    const int B = (N + SCAN_B - 1) / SCAN_B;

    // ws layout:
    //   deg[N] | offs[N+1] | bsums[B] | wsum[64] | bsum[1] | lut[LUTK+1] | pad |
    //   epack[E] int2 | pad | W1T | W2T | scf[128] | shf[128] | pad |
    //   rank[E] | pad | xq[N*128] int8 | pad | xscale[N] f32 | pad | aggh[N*128] bf16
    //   (deg_x[8*N] aliases the aggh region — dead until gather)
    char* ws = (char*)d_ws;
    int*   deg    = (int*)ws;
    int*   offs   = deg + N;
    int*   bsums  = offs + N + 1;
    float* wsumv  = (float*)(bsums + B);
    float* bsumv  = wsumv + NFILT;
    float* lut    = bsumv + 1;
    size_t hdr_ints  = (size_t)(2 * N + 1 + B + NFILT + 1 + LUTK + 1);
    size_t epack_off = ((hdr_ints * 4) + 15) & ~(size_t)15;
    int2*  epack  = (int2*)(ws + epack_off);
    size_t wT_off = (epack_off + (size_t)E * sizeof(int2) + 15) & ~(size_t)15;
    short* W1T    = (short*)(ws + wT_off);
    short* W2T    = W1T + HIDDEN * HIDDEN;
    float* scf    = (float*)(W2T + HIDDEN * HIDDEN);
    float* shf    = scf + HIDDEN;
    size_t base_need = wT_off + 2 * HIDDEN * HIDDEN * sizeof(short) + 2 * HIDDEN * sizeof(float);
    size_t rank_off  = (base_need + 15) & ~(size_t)15;
    int*   rank   = (int*)(ws + rank_off);
    size_t rank_need = rank_off + (size_t)E * sizeof(int);
    size_t xq_off    = (rank_need + 15) & ~(size_t)15;
    signed char* xq  = (signed char*)(ws + xq_off);
    size_t xs_off    = (xq_off + (size_t)N * HIDDEN + 15) & ~(size_t)15;
    float* xscale    = (float*)(ws + xs_off);
    size_t ag_off    = (xs_off + (size_t)N * sizeof(float) + 15) & ~(size_t)15;
    short* aggh      = (short*)(ws + ag_off);
    int*   deg_x     = (int*)aggh;   // alias: deg_x dead before gather writes aggh
    size_t bf_need   = ag_off + (size_t)N * HIDDEN * sizeof(short);

    if (ws_size >= base_need && B <= SCAN_B) {
        const bool use_rank = (ws_size >= rank_need);
        const bool use_bf   = (ws_size >= bf_need);   // implies use_rank
        if (!use_bf) {
            hipMemsetAsync(deg, 0, (size_t)N * sizeof(int), stream);
        }
        prep_w_kernel<<<128, 256, 0, stream>>>(Wi1, Wi2, W1T, W2T,
                                               Wf2, bf2, wsumv, bsumv,
                                               bi2, gam, bet, mmu, mva, scf, shf,
                                               use_bf ? deg_x : deg,
                                               use_bf ? NXCD * N : 0);
        lut_kernel<<<(LUTK + 256) / 256, 256, 0, stream>>>(Wf1, bf1, wsumv, bsumv, lut);
        if (use_bf) {
            int N16 = N * 16;                 // 16 lanes per node row
            int work = (N16 > E) ? N16 : E;
            x2q_count_kernel<<<(work + 255) / 256, 256, 0, stream>>>(x, xq, xscale, N16,
                                                                     rows, deg_x, rank,
                                                                     E, N);
            rowscan8_kernel<<<(N + 255) / 256, 256, 0, stream>>>(deg_x, deg, N);
        } else if (use_rank) {
            count_rank_kernel<<<(E + 255) / 256, 256, 0, stream>>>(rows, deg, rank, E);
        } else {
            count_kernel<<<(E + 255) / 256, 256, 0, stream>>>(rows, deg, E);
        }
        scan_p1<<<B, SCAN_B, 0, stream>>>(deg, bsums, N);
        scan_p2<<<1, SCAN_B, 0, stream>>>(bsums, B);
        if (use_bf) {
            scan_p3_t<false><<<B, SCAN_B, 0, stream>>>(deg, bsums, offs, N);
            fill_rank_q_kernel<<<(E + 255) / 256, 256, 0, stream>>>(rows, cols, ew, rank,
                                                                    offs, deg_x, xscale,
                                                                    lut, epack, E, N);
            gather_q8_kernel<<<(N + 15) / 16, 256, 0, stream>>>(offs, epack, xq, aggh, N);
            mlp_mfma_bf_kernel<<<(N + 127) / 128, 512, 0, stream>>>(aggh, io, W1T, W2T,
                                                                    bi1, scf, shf, N);
        } else if (use_rank) {
            scan_p3_t<false><<<B, SCAN_B, 0, stream>>>(deg, bsums, offs, N);
            fill_rank_kernel<<<(E + 255) / 256, 256, 0, stream>>>(rows, cols, ew, rank,
                                                                  offs, lut, epack, E);
            gather_kernel<<<(N + 7) / 8, 256, 0, stream>>>(offs, epack, x, io, N);
            mlp_mfma_kernel<<<(N + 63) / 64, 256, 0, stream>>>(io, W1T, W2T, bi1, scf, shf, N);
        } else {
            scan_p3_t<true><<<B, SCAN_B, 0, stream>>>(deg, bsums, offs, N);
            fill_cursor_kernel<<<(E + 255) / 256, 256, 0, stream>>>(rows, cols, ew, deg,
                                                                    lut, epack, E);
            gather_kernel<<<(N + 7) / 8, 256, 0, stream>>>(offs, epack, x, io, N);
            mlp_mfma_kernel<<<(N + 63) / 64, 256, 0, stream>>>(io, W1T, W2T, bi1, scf, shf, N);
        }
    } else {
        // ---- fallback: atomic scatter + fp32 MLP ----
        float* fs = (float*)d_ws;             // [E]
        float* w2 = fs + E;                   // [64]
        float* b2 = w2 + NFILT;               // [1]
        hipMemsetAsync(d_out, 0, (size_t)out_size * sizeof(float), stream);
        wsum_kernel<<<1, 64, 0, stream>>>(Wf2, bf2, w2, b2);
        edge_filter_kernel<<<(E + 255) / 256, 256, 0, stream>>>(ew, Wf1, bf1, w2, b2, fs, E);
        scatter_kernel<<<(E + 7) / 8, 256, 0, stream>>>(rows, cols, x, fs, io, E);
        mlp_kernel<<<(N + 63) / 64, 256, 0, stream>>>(io, Wi1, bi1, Wi2, bi2,
                                                      gam, bet, mmu, mva, N);
    }
}

// Round 9
// 342.239 us; speedup vs baseline: 1.0366x; 1.0265x over previous
//
#include <hip/hip_runtime.h>
#include <math.h>

#define HIDDEN 128
#define NFILT 64
#define SCAN_B 1024
#define LUTK 2048   // LUT entries over w in [0,8]; lerp err ~5e-7

typedef __attribute__((ext_vector_type(8))) short bf16x8;
typedef __attribute__((ext_vector_type(4))) float f32x4;
typedef __attribute__((ext_vector_type(4))) float f32x4v;
typedef __attribute__((ext_vector_type(2))) int i32x2;

__device__ __forceinline__ short f2bf(float f) {
    unsigned u = __float_as_uint(f);
    unsigned r = (u + 0x7fffu + ((u >> 16) & 1u)) >> 16;   // RNE
    return (short)r;
}
__device__ __forceinline__ float bf2f(unsigned short u) {
    return __uint_as_float(((unsigned)u) << 16);
}

// softplus via raw v_exp_f32/v_log_f32 (log2 domain): ~5 VALU instrs vs ~25+ for log1pf.
__device__ __forceinline__ float softplus_fast(float v) {
    float e = __builtin_amdgcn_exp2f(v * 1.4426950408889634f);
    float r = 0.69314718055994531f * __builtin_amdgcn_logf(1.0f + e);
    return (v > 80.f) ? v : r;   // exp2 overflow guard
}

// ---------------------------------------------------------------------------
// wsum[j] = sum_f Wf2[j][f]; bsum = sum_f bf2[f]   (fallback path only)
// ---------------------------------------------------------------------------
__global__ void wsum_kernel(const float* __restrict__ Wf2, const float* __restrict__ bf2,
                            float* __restrict__ wsum, float* __restrict__ bsum) {
    int j = threadIdx.x;  // 0..63
    float s = 0.f;
    for (int f = 0; f < NFILT; ++f) s += Wf2[j * NFILT + f];
    wsum[j] = s;
    if (j == 0) {
        float b = 0.f;
        for (int f = 0; f < NFILT; ++f) b += bf2[f];
        *bsum = b;
    }
}

__device__ __forceinline__ float edge_coeff(float w,
                                            const float* sW, const float* sB,
                                            const float* sS, float bsum) {
    float s = fmaf(w, 0.25f, -1.0f);          // w * (2/8) - 1
    float acc = bsum;
    #pragma unroll 8
    for (int j = 0; j < NFILT; ++j)
        acc += tanhf(fmaf(s, sW[j], sB[j])) * sS[j];
    float cut = (w <= 8.0f) ? 0.5f * (cosf(w * 0.39269908169872414f) + 1.0f) : 0.0f;
    return acc * cut;
}

// LUT over the scalar filter function g(w), w in [0,8], LUTK+1 samples
__global__ void lut_kernel(const float* __restrict__ Wf1, const float* __restrict__ bf1,
                           const float* __restrict__ wsum, const float* __restrict__ bsum,
                           float* __restrict__ lut) {
    int i = blockIdx.x * 256 + threadIdx.x;
    if (i > LUTK) return;
    float w = 8.0f * (float)i / (float)LUTK;
    lut[i] = edge_coeff(w, Wf1, bf1, wsum, *bsum);
}

__device__ __forceinline__ float lut_eval(const float* sl, float w) {
    float t = w * ((float)LUTK / 8.0f);
    t = fminf(fmaxf(t, 0.f), (float)LUTK);
    int i = (int)t;
    i = min(i, LUTK - 1);
    return fmaf(t - (float)i, sl[i + 1] - sl[i], sl[i]);
}

// ---------------------------------------------------------------------------
// Prep (fused): W1T/W2T bf16 transpose of Wi1/Wi2 (all blocks);
// block 0: wsum/bsum; block 1: BN fold; all blocks: grid-stride zero of zbuf
// (replaces the deg memset dispatch on the fast path).
// ---------------------------------------------------------------------------
__global__ void prep_w_kernel(const float* __restrict__ Wi1, const float* __restrict__ Wi2,
                              short* __restrict__ W1T, short* __restrict__ W2T,
                              const float* __restrict__ Wf2, const float* __restrict__ bf2,
                              float* __restrict__ wsum, float* __restrict__ bsum,
                              const float* __restrict__ bi2,
                              const float* __restrict__ gamma, const float* __restrict__ beta,
                              const float* __restrict__ mean, const float* __restrict__ var,
                              float* __restrict__ scf, float* __restrict__ shf,
                              int* __restrict__ zbuf, int zn) {
    int idx = blockIdx.x * 256 + threadIdx.x;   // 0..32767
    const float* src = (idx < 16384) ? Wi1 : Wi2;
    short* dst = (idx < 16384) ? W1T : W2T;
    int i = idx & 16383;
    int k = i >> 7, n = i & 127;
    dst[n * HIDDEN + k] = f2bf(src[i]);

    // zero deg (grid-stride, int4)
    for (int z = idx; z * 4 < zn; z += 32768) {
        if (z * 4 + 3 < zn) *(int4*)&zbuf[z * 4] = make_int4(0, 0, 0, 0);
        else for (int q = z * 4; q < zn; ++q) zbuf[q] = 0;
    }

    if (blockIdx.x == 0 && threadIdx.x < 64) {
        int j = threadIdx.x;
        float s = 0.f;
        for (int f = 0; f < NFILT; ++f) s += Wf2[j * NFILT + f];
        wsum[j] = s;
        if (j == 0) {
            float b = 0.f;
            for (int f = 0; f < NFILT; ++f) b += bf2[f];
            *bsum = b;
        }
    }
    if (blockIdx.x == 1 && threadIdx.x < HIDDEN) {
        int j = threadIdx.x;
        float sc = gamma[j] * rsqrtf(var[j] + 1e-3f);
        scf[j] = sc;
        shf[j] = (bi2[j] - mean[j]) * sc + beta[j];
    }
}

// ---------------------------------------------------------------------------
// Fused: x fp32 -> xq int8 per-row-scaled (streaming, NT reads) + CSR
// count/rank. The 1.6M scattered with-return atomics are serviced at a fixed
// ~23 G/s memory-side rate (measured floor, R6-R8) — the conversion work
// hides under the atomic stream.
// ---------------------------------------------------------------------------
__global__ __launch_bounds__(256) void x2q_count_kernel(
    const float* __restrict__ x, signed char* __restrict__ xq,
    float* __restrict__ xscale, int N16,
    const int* __restrict__ rows, int* __restrict__ deg,
    int* __restrict__ rank, int E) {
    int i = blockIdx.x * 256 + threadIdx.x;
    if (i < E) rank[i] = atomicAdd(&deg[rows[i]], 1);
    if (i < N16) {
        int node = i >> 4, lane = i & 15;
        const float* xp = &x[(size_t)node * HIDDEN + lane * 8];
        const f32x4v v0 = __builtin_nontemporal_load((const f32x4v*)xp);
        const f32x4v v1 = __builtin_nontemporal_load((const f32x4v*)(xp + 4));
        float v[8] = {v0[0], v0[1], v0[2], v0[3], v1[0], v1[1], v1[2], v1[3]};
        float m = 0.f;
        #pragma unroll
        for (int j = 0; j < 8; ++j) m = fmaxf(m, fabsf(v[j]));
        // reduce max across the 16 lanes of this node
        #pragma unroll
        for (int off = 8; off > 0; off >>= 1)
            m = fmaxf(m, __shfl_xor(m, off, 16));
        float si = (m > 0.f) ? 127.f / m : 0.f;
        int q[8];
        #pragma unroll
        for (int j = 0; j < 8; ++j) q[j] = __float2int_rn(v[j] * si);
        int lo = (q[0] & 0xff) | ((q[1] & 0xff) << 8) |
                 ((q[2] & 0xff) << 16) | ((q[3] & 0xff) << 24);
        int hi = (q[4] & 0xff) | ((q[5] & 0xff) << 8) |
                 ((q[6] & 0xff) << 16) | ((q[7] & 0xff) << 24);
        *(int2*)&xq[(size_t)node * HIDDEN + lane * 8] = make_int2(lo, hi);
        if (lane == 0) xscale[node] = m * (1.f / 127.f);
    }
}

// non-fused variants (tier B path)
__global__ void count_rank_kernel(const int* __restrict__ rows, int* __restrict__ deg,
                                  int* __restrict__ rank, int E) {
    int e = blockIdx.x * blockDim.x + threadIdx.x;
    if (e < E) rank[e] = atomicAdd(&deg[rows[e]], 1);
}

__global__ void count_kernel(const int* __restrict__ rows, int* __restrict__ deg, int E) {
    int e = blockIdx.x * blockDim.x + threadIdx.x;
    if (e < E) atomicAdd(&deg[rows[e]], 1);
}

__global__ __launch_bounds__(SCAN_B) void scan_p1(const int* __restrict__ deg,
                                                  int* __restrict__ bsums, int N) {
    __shared__ int red[SCAN_B];
    int i = blockIdx.x * SCAN_B + threadIdx.x;
    red[threadIdx.x] = (i < N) ? deg[i] : 0;
    __syncthreads();
    for (int off = SCAN_B / 2; off > 0; off >>= 1) {
        if (threadIdx.x < off) red[threadIdx.x] += red[threadIdx.x + off];
        __syncthreads();
    }
    if (threadIdx.x == 0) bsums[blockIdx.x] = red[0];
}

__global__ __launch_bounds__(SCAN_B) void scan_p2(int* __restrict__ bsums, int B) {
    __shared__ int part[SCAN_B];
    int t = threadIdx.x;
    part[t] = (t < B) ? bsums[t] : 0;
    __syncthreads();
    for (int off = 1; off < SCAN_B; off <<= 1) {
        int v = (t >= off) ? part[t - off] : 0;
        __syncthreads();
        part[t] += v;
        __syncthreads();
    }
    if (t < B) bsums[t] = (t == 0) ? 0 : part[t - 1];   // exclusive
}

template <bool WRITE_CURSOR>
__global__ __launch_bounds__(SCAN_B) void scan_p3_t(int* __restrict__ deg,
                                                    const int* __restrict__ bsums,
                                                    int* __restrict__ offs, int N) {
    __shared__ int part[SCAN_B];
    int t = threadIdx.x;
    int i = blockIdx.x * SCAN_B + t;
    int d = (i < N) ? deg[i] : 0;
    part[t] = d;
    __syncthreads();
    for (int off = 1; off < SCAN_B; off <<= 1) {
        int v = (t >= off) ? part[t - off] : 0;
        __syncthreads();
        part[t] += v;
        __syncthreads();
    }
    int pre = bsums[blockIdx.x] + part[t] - d;
    if (i < N) {
        offs[i] = pre;
        if (WRITE_CURSOR) deg[i] = pre;   // deg becomes cursor
        if (i == N - 1) offs[N] = pre + d;
    }
}

// fill (int8 path): pos = offs[row] + rank; coefficient folds the column's
// dequant scale: f' = g(w) * xscale[col]. xscale is 0.4 MB -> L2-resident.
__global__ __launch_bounds__(256) void fill_rank_q_kernel(
    const int* __restrict__ rows, const int* __restrict__ cols,
    const float* __restrict__ ew, const int* __restrict__ rank,
    const int* __restrict__ offs, const float* __restrict__ xscale,
    const float* __restrict__ lut, int2* __restrict__ epack, int E) {
    __shared__ float sl[LUTK + 1];
    for (int i = threadIdx.x; i <= LUTK; i += 256) sl[i] = lut[i];
    __syncthreads();
    int e = blockIdx.x * 256 + threadIdx.x;
    if (e >= E) return;
    float f = lut_eval(sl, __builtin_nontemporal_load(&ew[e]));
    int r = __builtin_nontemporal_load(&rows[e]);
    int c = __builtin_nontemporal_load(&cols[e]);
    float fs = f * xscale[c];
    int pos = offs[r] + __builtin_nontemporal_load(&rank[e]);
    epack[pos] = make_int2(c, __float_as_int(fs));
}

// fill (plain rank path, tier B)
__global__ __launch_bounds__(256) void fill_rank_kernel(
    const int* __restrict__ rows, const int* __restrict__ cols,
    const float* __restrict__ ew, const int* __restrict__ rank,
    const int* __restrict__ offs, const float* __restrict__ lut,
    int2* __restrict__ epack, int E) {
    __shared__ float sl[LUTK + 1];
    for (int i = threadIdx.x; i <= LUTK; i += 256) sl[i] = lut[i];
    __syncthreads();
    int e = blockIdx.x * 256 + threadIdx.x;
    if (e >= E) return;
    float f = lut_eval(sl, __builtin_nontemporal_load(&ew[e]));
    int pos = offs[__builtin_nontemporal_load(&rows[e])] +
              __builtin_nontemporal_load(&rank[e]);
    epack[pos] = make_int2(__builtin_nontemporal_load(&cols[e]), __float_as_int(f));
}

// fill (cursor path)
__global__ __launch_bounds__(256) void fill_cursor_kernel(
    const int* __restrict__ rows, const int* __restrict__ cols,
    const float* __restrict__ ew, int* __restrict__ cursor,
    const float* __restrict__ lut, int2* __restrict__ epack, int E) {
    __shared__ float sl[LUTK + 1];
    for (int i = threadIdx.x; i <= LUTK; i += 256) sl[i] = lut[i];
    __syncthreads();
    int e = blockIdx.x * 256 + threadIdx.x;
    if (e >= E) return;
    float f = lut_eval(sl, ew[e]);
    int pos = atomicAdd(&cursor[rows[e]], 1);
    epack[pos] = make_int2(cols[e], __float_as_int(f));
}

// ---------------------------------------------------------------------------
// gather (int8 xq): v2 — 8 lanes/node, int4 (16 B = 16 elems)/lane = 128 B
// per edge row, 4-deep pipeline -> 32 independent row-requests in flight per
// wave (2x R5). Dequant scale pre-folded into f; epack NT-loaded.
// ---------------------------------------------------------------------------
__device__ __forceinline__ void qfma8(int lo, int hi, float f, float* a) {
    a[0] = fmaf((float)((int)(((unsigned)lo) << 24) >> 24), f, a[0]);
    a[1] = fmaf((float)((int)(((unsigned)lo) << 16) >> 24), f, a[1]);
    a[2] = fmaf((float)((int)(((unsigned)lo) << 8) >> 24), f, a[2]);
    a[3] = fmaf((float)(lo >> 24), f, a[3]);
    a[4] = fmaf((float)((int)(((unsigned)hi) << 24) >> 24), f, a[4]);
    a[5] = fmaf((float)((int)(((unsigned)hi) << 16) >> 24), f, a[5]);
    a[6] = fmaf((float)((int)(((unsigned)hi) << 8) >> 24), f, a[6]);
    a[7] = fmaf((float)(hi >> 24), f, a[7]);
}

__device__ __forceinline__ void qfma16(int4 q, float f, float* a) {
    qfma8(q.x, q.y, f, a);
    qfma8(q.z, q.w, f, a + 8);
}

__global__ __launch_bounds__(256) void gather_q8_kernel(const int* __restrict__ offs,
                                                        const int2* __restrict__ epack,
                                                        const signed char* __restrict__ xq,
                                                        short* __restrict__ aggh, int N) {
    int t = threadIdx.x;
    int node = blockIdx.x * 32 + (t >> 3);
    if (node >= N) return;
    int lane = t & 7;
    int s = offs[node], eend = offs[node + 1];
    const signed char* xb = xq + lane * 16;

    float a[16];
    #pragma unroll
    for (int j = 0; j < 16; ++j) a[j] = 0.f;

    int i = s;
    for (; i + 4 <= eend; i += 4) {
        i32x2 p0 = __builtin_nontemporal_load((const i32x2*)&epack[i]);
        i32x2 p1 = __builtin_nontemporal_load((const i32x2*)&epack[i + 1]);
        i32x2 p2 = __builtin_nontemporal_load((const i32x2*)&epack[i + 2]);
        i32x2 p3 = __builtin_nontemporal_load((const i32x2*)&epack[i + 3]);
        int4 q0 = *(const int4*)(xb + (size_t)p0[0] * HIDDEN);
        int4 q1 = *(const int4*)(xb + (size_t)p1[0] * HIDDEN);
        int4 q2 = *(const int4*)(xb + (size_t)p2[0] * HIDDEN);
        int4 q3 = *(const int4*)(xb + (size_t)p3[0] * HIDDEN);
        qfma16(q0, __int_as_float(p0[1]), a);
        qfma16(q1, __int_as_float(p1[1]), a);
        qfma16(q2, __int_as_float(p2[1]), a);
        qfma16(q3, __int_as_float(p3[1]), a);
    }
    for (; i < eend; ++i) {
        i32x2 p = __builtin_nontemporal_load((const i32x2*)&epack[i]);
        int4 q = *(const int4*)(xb + (size_t)p[0] * HIDDEN);
        qfma16(q, __int_as_float(p[1]), a);
    }

    bf16x8 o0, o1;
    #pragma unroll
    for (int j = 0; j < 8; ++j) { o0[j] = f2bf(a[j]); o1[j] = f2bf(a[j + 8]); }
    short* op = &aggh[(size_t)node * HIDDEN + lane * 16];
    *(bf16x8*)op = o0;
    *(bf16x8*)(op + 8) = o1;
}

// fp32 variant (tier B/C)
__global__ __launch_bounds__(256) void gather_kernel(const int* __restrict__ offs,
                                                     const int2* __restrict__ epack,
                                                     const float* __restrict__ x,
                                                     float* __restrict__ agg, int N) {
    int t = threadIdx.x;
    int node = blockIdx.x * 8 + (t >> 5);
    if (node >= N) return;
    int lane = t & 31;
    int s = offs[node], eend = offs[node + 1];
    float4 acc = make_float4(0.f, 0.f, 0.f, 0.f);
    int i = s;
    for (; i + 2 <= eend; i += 2) {
        int2 p0 = epack[i];
        int2 p1 = epack[i + 1];
        float4 x0 = *(const float4*)&x[(size_t)p0.x * HIDDEN + lane * 4];
        float4 x1 = *(const float4*)&x[(size_t)p1.x * HIDDEN + lane * 4];
        float f0 = __int_as_float(p0.y), f1 = __int_as_float(p1.y);
        acc.x = fmaf(x0.x, f0, acc.x); acc.y = fmaf(x0.y, f0, acc.y);
        acc.z = fmaf(x0.z, f0, acc.z); acc.w = fmaf(x0.w, f0, acc.w);
        acc.x = fmaf(x1.x, f1, acc.x); acc.y = fmaf(x1.y, f1, acc.y);
        acc.z = fmaf(x1.z, f1, acc.z); acc.w = fmaf(x1.w, f1, acc.w);
    }
    for (; i < eend; ++i) {
        int2 p = epack[i];
        float f = __int_as_float(p.y);
        const float4 xv = *(const float4*)&x[(size_t)p.x * HIDDEN + lane * 4];
        acc.x = fmaf(xv.x, f, acc.x);
        acc.y = fmaf(xv.y, f, acc.y);
        acc.z = fmaf(xv.z, f, acc.z);
        acc.w = fmaf(xv.w, f, acc.w);
    }
    *(float4*)&agg[(size_t)node * HIDDEN + lane * 4] = acc;
}

// ---------------------------------------------------------------------------
// MFMA MLP (bf16 A from aggh; io fp32 out).
//   out = scf * (softplus(A @ Wi1 + bi1) @ Wi2) + shf
// W staged in LDS (XOR-swizzled, conflict-free ds_read_b128); W2 prefetched
// to regs during phase A; 512-thread / 128-row blocks; NT output stores.
// ---------------------------------------------------------------------------
#define HROW 136   // 128 + 8 shorts pad for the hS activation buffer

// W-tile swizzle: row = byte>>8 (256 B rows); spread 8 rows across 8 16B slots
#define WSWZ(b) ((b) ^ ((((b) >> 8) & 7) << 4))

__global__ __launch_bounds__(512) void mlp_mfma_bf_kernel(
    const short* __restrict__ aggh, float* __restrict__ io,
    const short* __restrict__ W1T, const short* __restrict__ W2T,
    const float* __restrict__ bi1,
    const float* __restrict__ scf, const float* __restrict__ shf,
    int N) {
    __shared__ short wS[HIDDEN * HIDDEN];   // 32 KB  (W1, then W2)
    __shared__ short hS[128 * HROW];        // 34.8 KB activations

    const int t = threadIdx.x;
    const int wave = t >> 6;        // 0..7
    const int lane = t & 63;
    const int quad = lane >> 4;
    const int m16  = lane & 15;
    const int row0 = blockIdx.x * 128 + wave * 16;
    const int arow = row0 + m16;

    const int swzmask = (m16 & 7) << 4;

    // ---- stage W1 -> LDS (swizzled); prefetch W2 into regs (held thru phase A)
    bf16x8 w2r[4];
    {
        const bf16x8* w1v = (const bf16x8*)W1T;
        const bf16x8* w2v = (const bf16x8*)W2T;
        bf16x8 w1r[4];
        #pragma unroll
        for (int j = 0; j < 4; ++j) w1r[j] = w1v[t + 512 * j];
        #pragma unroll
        for (int j = 0; j < 4; ++j) w2r[j] = w2v[t + 512 * j];
        #pragma unroll
        for (int j = 0; j < 4; ++j) {
            int b = (t + 512 * j) * 16;
            *(bf16x8*)((char*)wS + WSWZ(b)) = w1r[j];
        }
    }

    float b1v[8];
    #pragma unroll
    for (int ct = 0; ct < 8; ++ct) b1v[ct] = bi1[ct * 16 + m16];

    f32x4 acc[8];
    #pragma unroll
    for (int ct = 0; ct < 8; ++ct) acc[ct] = (f32x4)(0.f);

    __syncthreads();

    // ---- phase A: acc = aggh @ W1
    #pragma unroll
    for (int ks = 0; ks < 4; ++ks) {
        bf16x8 a;
        if (arow < N) {
            a = *(const bf16x8*)&aggh[(size_t)arow * HIDDEN + ks * 32 + quad * 8];
        } else {
            #pragma unroll
            for (int j = 0; j < 8; ++j) a[j] = 0;
        }
        const char* bbase = (const char*)wS + m16 * 256 + ((ks * 64 + quad * 16) ^ swzmask);
        #pragma unroll
        for (int ct = 0; ct < 8; ++ct) {
            bf16x8 b = *(const bf16x8*)(bbase + ct * 4096);
            acc[ct] = __builtin_amdgcn_mfma_f32_16x16x32_bf16(a, b, acc[ct], 0, 0, 0);
        }
    }

    // ---- epilogue A: +bi1, softplus, bf16 -> hS
    #pragma unroll
    for (int ct = 0; ct < 8; ++ct) {
        int col = ct * 16 + m16;
        #pragma unroll
        for (int r = 0; r < 4; ++r) {
            int lrow = wave * 16 + quad * 4 + r;
            float h = softplus_fast(acc[ct][r] + b1v[ct]);
            hS[lrow * HROW + col] = f2bf(h);
        }
        acc[ct] = (f32x4)(0.f);
    }
    __syncthreads();          // all waves done reading wS(W1) + hS complete

    // ---- stage W2 -> LDS from regs
    #pragma unroll
    for (int j = 0; j < 4; ++j) {
        int b = (t + 512 * j) * 16;
        *(bf16x8*)((char*)wS + WSWZ(b)) = w2r[j];
    }
    __syncthreads();

    float scv[8], shv[8];
    #pragma unroll
    for (int ct = 0; ct < 8; ++ct) {
        scv[ct] = scf[ct * 16 + m16];
        shv[ct] = shf[ct * 16 + m16];
    }

    // ---- phase B: acc = h @ W2
    #pragma unroll
    for (int ks = 0; ks < 4; ++ks) {
        bf16x8 a = *(const bf16x8*)&hS[(wave * 16 + m16) * HROW + ks * 32 + quad * 8];
        const char* bbase = (const char*)wS + m16 * 256 + ((ks * 64 + quad * 16) ^ swzmask);
        #pragma unroll
        for (int ct = 0; ct < 8; ++ct) {
            bf16x8 b = *(const bf16x8*)(bbase + ct * 4096);
            acc[ct] = __builtin_amdgcn_mfma_f32_16x16x32_bf16(a, b, acc[ct], 0, 0, 0);
        }
    }

    // ---- epilogue B: BN (folded) + NT fp32 store (write-once output)
    #pragma unroll
    for (int r = 0; r < 4; ++r) {
        int grow = row0 + quad * 4 + r;
        if (grow < N) {
            float* p = &io[(size_t)grow * HIDDEN + m16];
            #pragma unroll
            for (int ct = 0; ct < 8; ++ct)
                __builtin_nontemporal_store(fmaf(acc[ct][r], scv[ct], shv[ct]), p + ct * 16);
        }
    }
}

// fp32-A variant (tier B/C): in-place on io
__global__ __launch_bounds__(256) void mlp_mfma_kernel(
    float* io,
    const short* __restrict__ W1T, const short* __restrict__ W2T,
    const float* __restrict__ bi1,
    const float* __restrict__ scf, const float* __restrict__ shf,
    int N) {
    __shared__ short hS[64 * HROW];

    const int t = threadIdx.x;
    const int wave = t >> 6;
    const int lane = t & 63;
    const int quad = lane >> 4;
    const int m16  = lane & 15;
    const int row0 = blockIdx.x * 64 + wave * 16;
    const int arow = row0 + m16;

    f32x4 acc[8];
    #pragma unroll
    for (int ct = 0; ct < 8; ++ct) acc[ct] = (f32x4)(0.f);

    #pragma unroll
    for (int ks = 0; ks < 4; ++ks) {
        bf16x8 a;
        if (arow < N) {
            const float* ap = &io[(size_t)arow * HIDDEN + ks * 32 + quad * 8];
            float4 v0 = *(const float4*)ap;
            float4 v1 = *(const float4*)(ap + 4);
            a[0] = f2bf(v0.x); a[1] = f2bf(v0.y); a[2] = f2bf(v0.z); a[3] = f2bf(v0.w);
            a[4] = f2bf(v1.x); a[5] = f2bf(v1.y); a[6] = f2bf(v1.z); a[7] = f2bf(v1.w);
        } else {
            #pragma unroll
            for (int j = 0; j < 8; ++j) a[j] = 0;
        }
        #pragma unroll
        for (int ct = 0; ct < 8; ++ct) {
            bf16x8 b = *(const bf16x8*)&W1T[(ct * 16 + m16) * HIDDEN + ks * 32 + quad * 8];
            acc[ct] = __builtin_amdgcn_mfma_f32_16x16x32_bf16(a, b, acc[ct], 0, 0, 0);
        }
    }

    #pragma unroll
    for (int ct = 0; ct < 8; ++ct) {
        int col = ct * 16 + m16;
        float b1 = bi1[col];
        #pragma unroll
        for (int r = 0; r < 4; ++r) {
            int lrow = wave * 16 + quad * 4 + r;
            float h = softplus_fast(acc[ct][r] + b1);
            hS[lrow * HROW + col] = f2bf(h);
            acc[ct][r] = 0.f;
        }
    }
    __syncthreads();

    #pragma unroll
    for (int ks = 0; ks < 4; ++ks) {
        bf16x8 a = *(const bf16x8*)&hS[(wave * 16 + m16) * HROW + ks * 32 + quad * 8];
        #pragma unroll
        for (int ct = 0; ct < 8; ++ct) {
            bf16x8 b = *(const bf16x8*)&W2T[(ct * 16 + m16) * HIDDEN + ks * 32 + quad * 8];
            acc[ct] = __builtin_amdgcn_mfma_f32_16x16x32_bf16(a, b, acc[ct], 0, 0, 0);
        }
    }

    #pragma unroll
    for (int ct = 0; ct < 8; ++ct) {
        int col = ct * 16 + m16;
        float sc = scf[col], sh = shf[col];
        #pragma unroll
        for (int r = 0; r < 4; ++r) {
            int grow = row0 + quad * 4 + r;
            if (grow < N)
                io[(size_t)grow * HIDDEN + col] = fmaf(acc[ct][r], sc, sh);
        }
    }
}

// ---------------------------------------------------------------------------
// Fallback path kernels (tiny ws): atomic scatter + fp32 vector MLP
// ---------------------------------------------------------------------------
__global__ void edge_filter_kernel(const float* __restrict__ ew,
                                   const float* __restrict__ Wf1, const float* __restrict__ bf1,
                                   const float* __restrict__ wsum, const float* __restrict__ bsum,
                                   float* __restrict__ fs, int E) {
    __shared__ float sW[NFILT], sB[NFILT], sS[NFILT];
    if (threadIdx.x < NFILT) {
        sW[threadIdx.x] = Wf1[threadIdx.x];
        sB[threadIdx.x] = bf1[threadIdx.x];
        sS[threadIdx.x] = wsum[threadIdx.x];
    }
    __syncthreads();
    int e = blockIdx.x * blockDim.x + threadIdx.x;
    if (e >= E) return;
    fs[e] = edge_coeff(ew[e], sW, sB, sS, *bsum);
}

__global__ void scatter_kernel(const int* __restrict__ rows, const int* __restrict__ cols,
                               const float* __restrict__ x, const float* __restrict__ fs,
                               float* __restrict__ agg, int E) {
    int t = threadIdx.x;
    int e = blockIdx.x * 8 + (t >> 5);
    if (e >= E) return;
    int lane = t & 31;
    int r = rows[e];
    int c = cols[e];
    float f = fs[e];
    const float4 xv = *(const float4*)&x[c * HIDDEN + lane * 4];
    float* dst = &agg[r * HIDDEN + lane * 4];
    atomicAdd(dst + 0, xv.x * f);
    atomicAdd(dst + 1, xv.y * f);
    atomicAdd(dst + 2, xv.z * f);
    atomicAdd(dst + 3, xv.w * f);
}

__global__ __launch_bounds__(256) void mlp_kernel(
    float* __restrict__ io,
    const float* __restrict__ Wi1, const float* __restrict__ bi1,
    const float* __restrict__ Wi2, const float* __restrict__ bi2,
    const float* __restrict__ gamma, const float* __restrict__ beta,
    const float* __restrict__ mean, const float* __restrict__ var,
    int N) {
    __shared__ float As[64 * HIDDEN];
    __shared__ float Wh[64 * HIDDEN];

    const int t = threadIdx.x;
    const int row0 = blockIdx.x * 64;
    const int col4 = (t & 31) * 4;
    const int rgrp = t >> 5;

    #pragma unroll
    for (int i = 0; i < 8; ++i) {
        int f4 = t + 256 * i;
        int r = f4 >> 5, c4 = (f4 & 31) * 4;
        int node = row0 + r;
        float4 v = make_float4(0.f, 0.f, 0.f, 0.f);
        if (node < N) v = *(const float4*)&io[node * HIDDEN + c4];
        *(float4*)&As[r * HIDDEN + c4] = v;
    }

    float acc[8][4];
    #pragma unroll
    for (int r = 0; r < 8; ++r)
        for (int j = 0; j < 4; ++j) acc[r][j] = 0.f;

    for (int kh = 0; kh < 2; ++kh) {
        __syncthreads();
        #pragma unroll
        for (int i = 0; i < 8; ++i) {
            int f4 = t + 256 * i;
            int kr = f4 >> 5, c4 = (f4 & 31) * 4;
            *(float4*)&Wh[kr * HIDDEN + c4] = *(const float4*)&Wi1[(kh * 64 + kr) * HIDDEN + c4];
        }
        __syncthreads();
        for (int k = 0; k < 64; ++k) {
            float4 w = *(const float4*)&Wh[k * HIDDEN + col4];
            #pragma unroll
            for (int r = 0; r < 8; ++r) {
                float a = As[(rgrp + 8 * r) * HIDDEN + kh * 64 + k];
                acc[r][0] = fmaf(a, w.x, acc[r][0]);
                acc[r][1] = fmaf(a, w.y, acc[r][1]);
                acc[r][2] = fmaf(a, w.z, acc[r][2]);
                acc[r][3] = fmaf(a, w.w, acc[r][3]);
            }
        }
    }
    __syncthreads();

    {
        float4 b = *(const float4*)&bi1[col4];
        float bv[4] = {b.x, b.y, b.z, b.w};
        #pragma unroll
        for (int r = 0; r < 8; ++r) {
            float hv[4];
            #pragma unroll
            for (int j = 0; j < 4; ++j) {
                float v = acc[r][j] + bv[j];
                hv[j] = softplus_fast(v);
                acc[r][j] = 0.f;
            }
            *(float4*)&As[(rgrp + 8 * r) * HIDDEN + col4] =
                make_float4(hv[0], hv[1], hv[2], hv[3]);
        }
    }

    for (int kh = 0; kh < 2; ++kh) {
        __syncthreads();
        #pragma unroll
        for (int i = 0; i < 8; ++i) {
            int f4 = t + 256 * i;
            int kr = f4 >> 5, c4 = (f4 & 31) * 4;
            *(float4*)&Wh[kr * HIDDEN + c4] = *(const float4*)&Wi2[(kh * 64 + kr) * HIDDEN + c4];
        }
        __syncthreads();
        for (int k = 0; k < 64; ++k) {
            float4 w = *(const float4*)&Wh[k * HIDDEN + col4];
            #pragma unroll
            for (int r = 0; r < 8; ++r) {
                float a = As[(rgrp + 8 * r) * HIDDEN + kh * 64 + k];
                acc[r][0] = fmaf(a, w.x, acc[r][0]);
                acc[r][1] = fmaf(a, w.y, acc[r][1]);
                acc[r][2] = fmaf(a, w.z, acc[r][2]);
                acc[r][3] = fmaf(a, w.w, acc[r][3]);
            }
        }
    }

    {
        float4 b2 = *(const float4*)&bi2[col4];
        float4 g  = *(const float4*)&gamma[col4];
        float4 be = *(const float4*)&beta[col4];
        float4 mu = *(const float4*)&mean[col4];
        float4 va = *(const float4*)&var[col4];
        float bv[4]  = {b2.x, b2.y, b2.z, b2.w};
        float gv[4]  = {g.x, g.y, g.z, g.w};
        float bev[4] = {be.x, be.y, be.z, be.w};
        float muv[4] = {mu.x, mu.y, mu.z, mu.w};
        float vav[4] = {va.x, va.y, va.z, va.w};
        float sc[4];
        #pragma unroll
        for (int j = 0; j < 4; ++j) sc[j] = gv[j] * rsqrtf(vav[j] + 1e-3f);
        #pragma unroll
        for (int r = 0; r < 8; ++r) {
            int node = row0 + rgrp + 8 * r;
            if (node < N) {
                float o[4];
                #pragma unroll
                for (int j = 0; j < 4; ++j)
                    o[j] = (acc[r][j] + bv[j] - muv[j]) * sc[j] + bev[j];
                *(float4*)&io[node * HIDDEN + col4] = make_float4(o[0], o[1], o[2], o[3]);
            }
        }
    }
}

extern "C" void kernel_launch(void* const* d_in, const int* in_sizes, int n_in,
                              void* d_out, int out_size, void* d_ws, size_t ws_size,
                              hipStream_t stream) {
    const float* x    = (const float*)d_in[0];
    const int*   ei   = (const int*)d_in[1];
    const float* ew   = (const float*)d_in[2];
    // d_in[3] = edge_attr: unused by the reference math
    const float* Wf1  = (const float*)d_in[4];
    const float* bf1  = (const float*)d_in[5];
    const float* Wf2  = (const float*)d_in[6];
    const float* bf2  = (const float*)d_in[7];
    const float* Wi1  = (const float*)d_in[8];
    const float* bi1  = (const float*)d_in[9];
    const float* Wi2  = (const float*)d_in[10];
    const float* bi2  = (const float*)d_in[11];
    const float* gam  = (const float*)d_in[12];
    const float* bet  = (const float*)d_in[13];
    const float* mmu  = (const float*)d_in[14];
    const float* mva  = (const float*)d_in[15];

    const int N = in_sizes[0] / HIDDEN;
    const int E = in_sizes[2];
    const int* rows = ei;
    const int* cols = ei + E;

    float* io = (float*)d_out;     // final output; tier B/C also use it as agg

    const int B = (N + SCAN_B - 1) / SCAN_B;

    // ws layout:
    //   deg[N] | offs[N+1] | bsums[B] | wsum[64] | bsum[1] | lut[LUTK+1] | pad |
    //   epack[E] int2 | pad | W1T | W2T | scf[128] | shf[128] | pad |
    //   rank[E] | pad | xq[N*128] int8 | pad | xscale[N] f32 | pad | aggh[N*128] bf16
    char* ws = (char*)d_ws;
    int*   deg    = (int*)ws;
    int*   offs   = deg + N;
    int*   bsums  = offs + N + 1;
    float* wsumv  = (float*)(bsums + B);
    float* bsumv  = wsumv + NFILT;
    float* lut    = bsumv + 1;
    size_t hdr_ints  = (size_t)(2 * N + 1 + B + NFILT + 1 + LUTK + 1);
    size_t epack_off = ((hdr_ints * 4) + 15) & ~(size_t)15;
    int2*  epack  = (int2*)(ws + epack_off);
    size_t wT_off = (epack_off + (size_t)E * sizeof(int2) + 15) & ~(size_t)15;
    short* W1T    = (short*)(ws + wT_off);
    short* W2T    = W1T + HIDDEN * HIDDEN;
    float* scf    = (float*)(W2T + HIDDEN * HIDDEN);
    float* shf    = scf + HIDDEN;
    size_t base_need = wT_off + 2 * HIDDEN * HIDDEN * sizeof(short) + 2 * HIDDEN * sizeof(float);
    size_t rank_off  = (base_need + 15) & ~(size_t)15;
    int*   rank   = (int*)(ws + rank_off);
    size_t rank_need = rank_off + (size_t)E * sizeof(int);
    size_t xq_off    = (rank_need + 15) & ~(size_t)15;
    signed char* xq  = (signed char*)(ws + xq_off);
    size_t xs_off    = (xq_off + (size_t)N * HIDDEN + 15) & ~(size_t)15;
    float* xscale    = (float*)(ws + xs_off);
    size_t ag_off    = (xs_off + (size_t)N * sizeof(float) + 15) & ~(size_t)15;
    short* aggh      = (short*)(ws + ag_off);
    size_t bf_need   = ag_off + (size_t)N * HIDDEN * sizeof(short);

    if (ws_size >= base_need && B <= SCAN_B) {
        const bool use_rank = (ws_size >= rank_need);
        const bool use_bf   = (ws_size >= bf_need);   // implies use_rank
        if (!use_bf) {
            hipMemsetAsync(deg, 0, (size_t)N * sizeof(int), stream);
        }
        prep_w_kernel<<<128, 256, 0, stream>>>(Wi1, Wi2, W1T, W2T,
                                               Wf2, bf2, wsumv, bsumv,
                                               bi2, gam, bet, mmu, mva, scf, shf,
                                               deg, use_bf ? N : 0);
        lut_kernel<<<(LUTK + 256) / 256, 256, 0, stream>>>(Wf1, bf1, wsumv, bsumv, lut);
        if (use_bf) {
            int N16 = N * 16;                 // 16 lanes per node row
            int work = (N16 > E) ? N16 : E;
            x2q_count_kernel<<<(work + 255) / 256, 256, 0, stream>>>(x, xq, xscale, N16,
                                                                     rows, deg, rank, E);
        } else if (use_rank) {
            count_rank_kernel<<<(E + 255) / 256, 256, 0, stream>>>(rows, deg, rank, E);
        } else {
            count_kernel<<<(E + 255) / 256, 256, 0, stream>>>(rows, deg, E);
        }
        scan_p1<<<B, SCAN_B, 0, stream>>>(deg, bsums, N);
        scan_p2<<<1, SCAN_B, 0, stream>>>(bsums, B);
        if (use_bf) {
            scan_p3_t<false><<<B, SCAN_B, 0, stream>>>(deg, bsums, offs, N);
            fill_rank_q_kernel<<<(E + 255) / 256, 256, 0, stream>>>(rows, cols, ew, rank,
                                                                    offs, xscale, lut,
                                                                    epack, E);
            gather_q8_kernel<<<(N + 31) / 32, 256, 0, stream>>>(offs, epack, xq, aggh, N);
            mlp_mfma_bf_kernel<<<(N + 127) / 128, 512, 0, stream>>>(aggh, io, W1T, W2T,
                                                                    bi1, scf, shf, N);
        } else if (use_rank) {
            scan_p3_t<false><<<B, SCAN_B, 0, stream>>>(deg, bsums, offs, N);
            fill_rank_kernel<<<(E + 255) / 256, 256, 0, stream>>>(rows, cols, ew, rank,
                                                                  offs, lut, epack, E);
            gather_kernel<<<(N + 7) / 8, 256, 0, stream>>>(offs, epack, x, io, N);
            mlp_mfma_kernel<<<(N + 63) / 64, 256, 0, stream>>>(io, W1T, W2T, bi1, scf, shf, N);
        } else {
            scan_p3_t<true><<<B, SCAN_B, 0, stream>>>(deg, bsums, offs, N);
            fill_cursor_kernel<<<(E + 255) / 256, 256, 0, stream>>>(rows, cols, ew, deg,
                                                                    lut, epack, E);
            gather_kernel<<<(N + 7) / 8, 256, 0, stream>>>(offs, epack, x, io, N);
            mlp_mfma_kernel<<<(N + 63) / 64, 256, 0, stream>>>(io, W1T, W2T, bi1, scf, shf, N);
        }
    } else {
        // ---- fallback: atomic scatter + fp32 MLP ----
        float* fs = (float*)d_ws;             // [E]
        float* w2 = fs + E;                   // [64]
        float* b2 = w2 + NFILT;               // [1]
        hipMemsetAsync(d_out, 0, (size_t)out_size * sizeof(float), stream);
        wsum_kernel<<<1, 64, 0, stream>>>(Wf2, bf2, w2, b2);
        edge_filter_kernel<<<(E + 255) / 256, 256, 0, stream>>>(ew, Wf1, bf1, w2, b2, fs, E);
        scatter_kernel<<<(E + 7) / 8, 256, 0, stream>>>(rows, cols, x, fs, io, E);
        mlp_kernel<<<(N + 63) / 64, 256, 0, stream>>>(io, Wi1, bi1, Wi2, bi2,
                                                      gam, bet, mmu, mva, N);
    }
}